// Round 1
// baseline (194077.979 us; speedup 1.0000x reference)
//
#include <hip/hip_runtime.h>
#include <hip/hip_bf16.h>

typedef __hip_bfloat16 bf16;

__device__ __forceinline__ float toF(float v) { return v; }
__device__ __forceinline__ float toF(bf16 v) { return __bfloat162float(v); }

// ---------------------------------------------------------------- convert x
__global__ void f32_to_bf16(const float* __restrict__ in, bf16* __restrict__ out, size_t n) {
  size_t i = (size_t)blockIdx.x * blockDim.x + threadIdx.x;
  size_t stride = (size_t)gridDim.x * blockDim.x;
  for (; i < n; i += stride) out[i] = __float2bfloat16(in[i]);
}

// ---------------------------------------------------------------- conv 3x3 SAME + bias + relu
// One block: (n, co, 16x16 spatial tile). Weights for co staged in LDS (fp32),
// input tile staged 8 channels at a time (18x18 halo tile, bf16). fp32 accumulate.
__global__ __launch_bounds__(256) void conv3x3_relu(
    const bf16* __restrict__ in, const float* __restrict__ w,
    const float* __restrict__ bias, bf16* __restrict__ out,
    int Cin, int Cout, int H, int W)
{
  __shared__ float wlds[512 * 9];          // 18 KB max (Cin<=512)
  __shared__ bf16 itile[8][18][18];        // 5.1 KB
  const int n  = blockIdx.z / Cout;
  const int co = blockIdx.z % Cout;
  const int h0 = blockIdx.y * 16;
  const int w0 = blockIdx.x * 16;
  const int tid = threadIdx.x;
  const int ty = tid >> 4, tx = tid & 15;

  const int nW = Cin * 9;
  for (int i = tid; i < nW; i += 256) wlds[i] = w[(size_t)co * nW + i];

  const bf16* inN = in + (size_t)n * Cin * H * W;
  float acc = 0.f;

  for (int c0 = 0; c0 < Cin; c0 += 8) {
    const int cc = (Cin - c0 < 8) ? (Cin - c0) : 8;
    __syncthreads();   // protect itile from previous iter's readers; orders wlds writes too
    const int tot = cc * 324;
    for (int i = tid; i < tot; i += 256) {
      int ci = i / 324;
      int r  = i - ci * 324;
      int tyi = r / 18, txi = r - tyi * 18;
      int hi = h0 - 1 + tyi, wi = w0 - 1 + txi;
      bf16 v = __float2bfloat16(0.f);
      if (hi >= 0 && hi < H && wi >= 0 && wi < W)
        v = inN[(size_t)(c0 + ci) * H * W + (size_t)hi * W + wi];
      itile[ci][tyi][txi] = v;
    }
    __syncthreads();
    for (int ci = 0; ci < cc; ++ci) {
      const float* wp = &wlds[(c0 + ci) * 9];
      #pragma unroll
      for (int kh = 0; kh < 3; ++kh) {
        #pragma unroll
        for (int kw = 0; kw < 3; ++kw) {
          acc += __bfloat162float(itile[ci][ty + kh][tx + kw]) * wp[kh * 3 + kw];
        }
      }
    }
  }

  const int h = h0 + ty, ww = w0 + tx;
  if (h < H && ww < W) {
    float r = fmaxf(acc + bias[co], 0.f);
    out[((size_t)n * Cout + co) * H * W + (size_t)h * W + ww] = __float2bfloat16(r);
  }
}

// ---------------------------------------------------------------- maxpool 2x2 stride 2
__global__ void maxpool2x2(const bf16* __restrict__ in, bf16* __restrict__ out,
                           int NC, int H, int W) {
  const int H2 = H >> 1, W2 = W >> 1;
  size_t total = (size_t)NC * H2 * W2;
  for (size_t i = (size_t)blockIdx.x * blockDim.x + threadIdx.x; i < total;
       i += (size_t)gridDim.x * blockDim.x) {
    int wo = (int)(i % W2);
    size_t t = i / W2;
    int ho = (int)(t % H2);
    size_t nc = t / H2;
    const bf16* p = in + (nc * H + 2 * ho) * (size_t)W + 2 * wo;
    float a = __bfloat162float(p[0]),     b = __bfloat162float(p[1]);
    float c = __bfloat162float(p[W]),     d = __bfloat162float(p[W + 1]);
    out[i] = __float2bfloat16(fmaxf(fmaxf(a, b), fmaxf(c, d)));
  }
}

// ---------------------------------------------------------------- FC (thread per output)
template <typename TIN, bool RELU>
__global__ void fc_kernel(const TIN* __restrict__ in, const float* __restrict__ w,
                          const float* __restrict__ bias, float* __restrict__ out,
                          int fin, int fout) {
  const int n = blockIdx.y;
  const int j = blockIdx.x * blockDim.x + threadIdx.x;
  if (j >= fout) return;
  const TIN* ip = in + (size_t)n * fin;
  float acc = bias[j];
  int k = 0;
  #pragma unroll 1
  for (; k + 16 <= fin; k += 16) {
    #pragma unroll
    for (int u = 0; u < 16; ++u)
      acc += toF(ip[k + u]) * w[(size_t)(k + u) * fout + j];
  }
  for (; k < fin; ++k) acc += toF(ip[k]) * w[(size_t)k * fout + j];
  if (RELU) acc = fmaxf(acc, 0.f);
  out[(size_t)n * fout + j] = acc;
}

// ---------------------------------------------------------------- launch
extern "C" void kernel_launch(void* const* d_in, const int* in_sizes, int n_in,
                              void* d_out, int out_size, void* d_ws, size_t ws_size,
                              hipStream_t stream) {
  const float* x = (const float*)d_in[0];
  const float* cw[13];
  const float* cb[13];
  for (int i = 0; i < 13; ++i) {
    cw[i] = (const float*)d_in[1 + 2 * i];
    cb[i] = (const float*)d_in[2 + 2 * i];
  }
  const float* fw1 = (const float*)d_in[27]; const float* fb1 = (const float*)d_in[28];
  const float* fw2 = (const float*)d_in[29]; const float* fb2 = (const float*)d_in[30];
  const float* fw3 = (const float*)d_in[31]; const float* fb3 = (const float*)d_in[32];
  float* outp = (float*)d_out;

  const int N = 16;
  const size_t ELEMS = 52000000;      // > 16*64*224*224 = 51.38M (largest activation)
  bf16* A = (bf16*)d_ws;
  bf16* B = A + ELEMS;                // byte offset 104,000,000
  float* F1 = (float*)(B + ELEMS);    // byte offset 208,000,000 (256B aligned)
  float* F2 = F1 + (size_t)N * 4096;

  // x (fp32) -> bf16 in A
  {
    size_t nx = (size_t)N * 3 * 224 * 224;
    f32_to_bf16<<<2048, 256, 0, stream>>>(x, A, nx);
  }

  auto conv = [&](const bf16* pin, bf16* pout, int li, int Cin, int Cout, int H, int W) {
    dim3 g((W + 15) / 16, (H + 15) / 16, N * Cout);
    conv3x3_relu<<<g, 256, 0, stream>>>(pin, cw[li], cb[li], pout, Cin, Cout, H, W);
  };
  auto pool = [&](const bf16* pin, bf16* pout, int C, int H, int W) {
    size_t total = (size_t)N * C * (H / 2) * (W / 2);
    int blocks = (int)((total + 255) / 256);
    if (blocks > 2048) blocks = 2048;
    maxpool2x2<<<blocks, 256, 0, stream>>>(pin, pout, N * C, H, W);
  };

  conv(A, B, 0, 3, 64, 224, 224);
  conv(B, A, 1, 64, 64, 224, 224);
  pool(A, B, 64, 224, 224);

  conv(B, A, 2, 64, 128, 112, 112);
  conv(A, B, 3, 128, 128, 112, 112);
  pool(B, A, 128, 112, 112);

  conv(A, B, 4, 128, 256, 56, 56);
  conv(B, A, 5, 256, 256, 56, 56);
  conv(A, B, 6, 256, 256, 56, 56);
  pool(B, A, 256, 56, 56);

  conv(A, B, 7, 256, 512, 28, 28);
  conv(B, A, 8, 512, 512, 28, 28);
  conv(A, B, 9, 512, 512, 28, 28);
  pool(B, A, 512, 28, 28);

  conv(A, B, 10, 512, 512, 14, 14);
  conv(B, A, 11, 512, 512, 14, 14);
  conv(A, B, 12, 512, 512, 14, 14);
  pool(B, A, 512, 14, 14);   // -> A: [16, 512, 7, 7] bf16 == flattened FC input

  fc_kernel<bf16, true ><<<dim3(16, N), 256, 0, stream>>>(A,  fw1, fb1, F1,   25088, 4096);
  fc_kernel<float, true ><<<dim3(16, N), 256, 0, stream>>>(F1, fw2, fb2, F2,   4096, 4096);
  fc_kernel<float, false><<<dim3(4,  N), 256, 0, stream>>>(F2, fw3, fb3, outp, 4096, 1000);
}

// Round 2
// 2666.678 us; speedup vs baseline: 72.7789x; 72.7789x over previous
//
#include <hip/hip_runtime.h>
#include <hip/hip_bf16.h>

typedef __hip_bfloat16 bf16;
typedef __attribute__((ext_vector_type(8))) short short8;
typedef __attribute__((ext_vector_type(8))) __bf16 bf16x8;
typedef __attribute__((ext_vector_type(4))) float f32x4;

__device__ __forceinline__ float s2f(short s) {
  return __builtin_bit_cast(float, (unsigned)((unsigned short)s) << 16);
}
__device__ __forceinline__ short f2s(float f) {
  return __builtin_bit_cast(short, __float2bfloat16(f));
}

__device__ __forceinline__ void gl16(const bf16* g, bf16* l) {
  __builtin_amdgcn_global_load_lds(
      (const __attribute__((address_space(1))) void*)g,
      (__attribute__((address_space(3))) void*)l, 16, 0, 0);
}

// ---------------------------------------------------------------- zero fill (zpage)
__global__ void zerofill(float* p, int n) {
  int i = blockIdx.x * 256 + threadIdx.x;
  if (i < n) p[i] = 0.f;
}

// ---------------------------------------------------------------- layer 1: 3->64, fp32 NCHW in, bf16 NHWC out
__global__ __launch_bounds__(256) void conv1_first(
    const float* __restrict__ x, const float* __restrict__ w,
    const float* __restrict__ b, bf16* __restrict__ out) {
  __shared__ float it[3][18][18];
  __shared__ float wl[1728];
  __shared__ float bl[64];
  const int tid = threadIdx.x;
  const int n = blockIdx.z;
  const int h0 = blockIdx.y * 16, w0 = blockIdx.x * 16;
  for (int i = tid; i < 1728; i += 256) wl[i] = w[i];
  if (tid < 64) bl[tid] = b[tid];
  for (int i = tid; i < 972; i += 256) {
    int ci = i / 324; int r = i - ci * 324; int ty = r / 18, tx = r - ty * 18;
    int hh = h0 - 1 + ty, ww = w0 - 1 + tx;
    float v = 0.f;
    if (hh >= 0 && hh < 224 && ww >= 0 && ww < 224)
      v = x[((long)n * 3 + ci) * 50176 + hh * 224 + ww];
    it[ci][ty][tx] = v;
  }
  __syncthreads();
  const int ty = tid >> 4, tx = tid & 15;
  long ob = (((long)n * 224 + h0 + ty) * 224 + (w0 + tx)) * 64;
  for (int cog = 0; cog < 4; ++cog) {
    float acc[16];
    #pragma unroll
    for (int u = 0; u < 16; ++u) acc[u] = bl[cog * 16 + u];
    #pragma unroll
    for (int ci = 0; ci < 3; ++ci)
      #pragma unroll
      for (int kh = 0; kh < 3; ++kh)
        #pragma unroll
        for (int kw = 0; kw < 3; ++kw) {
          float v = it[ci][ty + kh][tx + kw];
          int jj = ci * 9 + kh * 3 + kw;
          #pragma unroll
          for (int u = 0; u < 16; ++u) acc[u] += v * wl[(cog * 16 + u) * 27 + jj];
        }
    short8 s0, s1;
    #pragma unroll
    for (int u = 0; u < 8; ++u) {
      s0[u] = f2s(fmaxf(acc[u], 0.f));
      s1[u] = f2s(fmaxf(acc[8 + u], 0.f));
    }
    *(short8*)(out + ob + cog * 16) = s0;
    *(short8*)(out + ob + cog * 16 + 8) = s1;
  }
}

// ---------------------------------------------------------------- weight repack: OIHW fp32 -> [Cout][K] bf16, K=(kh*3+kw)*Cin+ci
__global__ void repack_w(const float* __restrict__ w, bf16* __restrict__ wp,
                         int Cin, int cshift, int K) {
  int co = blockIdx.y;
  int k = blockIdx.x * 256 + threadIdx.x;
  if (k < K) {
    int pos = k >> cshift;
    int ci = k & (Cin - 1);
    wp[(long)co * K + k] = __float2bfloat16(w[((long)co * Cin + ci) * 9 + pos]);
  }
}

// ---------------------------------------------------------------- implicit-GEMM conv (NHWC, bf16 MFMA)
// C[p, co] = sum_k A[p,k] * Wp[co,k];  k = pos*Cin + ci, pos=(kh*3+kw)
// per-wave output 64x64; BK=64; XOR-swizzled LDS (both sides, rule #21)
template <int BM, int BN, int WM, int WN>
__global__ __launch_bounds__(WM* WN * 64) void conv_gemm(
    const bf16* __restrict__ in, const bf16* __restrict__ wp,
    const float* __restrict__ bias, bf16* __restrict__ out,
    const bf16* __restrict__ zp,
    int Cin, int cshift, int Cout, int H, int W, int NHW) {
  constexpr int NT = WM * WN * 64;
  constexpr int IA = BM * 8 / NT;   // gload_lds per thread for A tile
  constexpr int IB = BN * 8 / NT;
  __shared__ bf16 lA[BM * 64];
  __shared__ bf16 lB[BN * 64];
  const int tid = threadIdx.x;
  const int lane = tid & 63, wv = tid >> 6;
  const int wr = wv / WN, wc = wv % WN;
  const int p0 = blockIdx.x * BM;
  const int co0 = blockIdx.y * BN;
  const int K = 9 << cshift;
  const int HW = H * W;
  // swizzled k-segment (elements), constant per thread for both A and B staging
  const int colx = ((tid & 7) ^ ((tid >> 3) & 7)) * 8;

  int baseA[IA]; short hA[IA], wA[IA];
  #pragma unroll
  for (int i = 0; i < IA; ++i) {
    int r = i * (NT / 8) + (tid >> 3);
    int p = p0 + r;
    if (p < NHW) {
      int n = p / HW; int rem = p - n * HW; int h = rem / W; int w_ = rem - h * W;
      hA[i] = (short)h; wA[i] = (short)w_;
      baseA[i] = ((n * H + h) * W + w_) * Cin;
    } else { hA[i] = -9999; wA[i] = -9999; baseA[i] = 0; }
  }

  f32x4 acc[4][4];
  #pragma unroll
  for (int m = 0; m < 4; ++m)
    #pragma unroll
    for (int n2 = 0; n2 < 4; ++n2) acc[m][n2] = (f32x4){0.f, 0.f, 0.f, 0.f};

  for (int k0 = 0; k0 < K; k0 += 64) {
    const int pos = k0 >> cshift;
    const int dh = pos / 3 - 1, dw = pos % 3 - 1;
    const int ciB = k0 & (Cin - 1);
    const int doff = (dh * W + dw) * Cin + ciB + colx;
    __syncthreads();
    #pragma unroll
    for (int i = 0; i < IA; ++i) {
      int hh = hA[i] + dh, ww = wA[i] + dw;
      bool ok = (hh >= 0) & (hh < H) & (ww >= 0) & (ww < W);
      const bf16* src = ok ? (in + baseA[i] + doff) : zp;
      gl16(src, lA + i * (NT * 8) + wv * 512);
    }
    #pragma unroll
    for (int i = 0; i < IB; ++i) {
      int col = i * (NT / 8) + (tid >> 3);
      const bf16* src = wp + (long)(co0 + col) * K + k0 + colx;
      gl16(src, lB + i * (NT * 8) + wv * 512);
    }
    __syncthreads();
    #pragma unroll
    for (int ks = 0; ks < 2; ++ks) {
      const int kb = ks * 64 + (lane >> 4) * 16;  // byte offset in row
      bf16x8 af[4], bfv[4];
      #pragma unroll
      for (int m = 0; m < 4; ++m) {
        int r = wr * 64 + m * 16 + (lane & 15);
        af[m] = *(const bf16x8*)((const char*)lA + r * 128 + (kb ^ ((r & 7) << 4)));
      }
      #pragma unroll
      for (int n2 = 0; n2 < 4; ++n2) {
        int c = wc * 64 + n2 * 16 + (lane & 15);
        bfv[n2] = *(const bf16x8*)((const char*)lB + c * 128 + (kb ^ ((c & 7) << 4)));
      }
      #pragma unroll
      for (int m = 0; m < 4; ++m)
        #pragma unroll
        for (int n2 = 0; n2 < 4; ++n2)
          acc[m][n2] = __builtin_amdgcn_mfma_f32_16x16x32_bf16(af[m], bfv[n2], acc[m][n2], 0, 0, 0);
    }
  }

  // epilogue: C/D layout col=lane&15, row=(lane>>4)*4+q
  #pragma unroll
  for (int m = 0; m < 4; ++m) {
    int pb = p0 + wr * 64 + m * 16 + (lane >> 4) * 4;
    #pragma unroll
    for (int n2 = 0; n2 < 4; ++n2) {
      int co = co0 + wc * 64 + n2 * 16 + (lane & 15);
      float bb = bias[co];
      #pragma unroll
      for (int q = 0; q < 4; ++q) {
        int pp = pb + q;
        if (pp < NHW)
          out[(long)pp * Cout + co] = __float2bfloat16(fmaxf(acc[m][n2][q] + bb, 0.f));
      }
    }
  }
}

// ---------------------------------------------------------------- maxpool 2x2 NHWC (short8 vectors)
__global__ void maxpool_nhwc(const bf16* __restrict__ in, bf16* __restrict__ out,
                             int H, int W, int C, int cshift3, int WC8) {
  const int id = blockIdx.x * 256 + threadIdx.x;
  if (id >= WC8) return;
  const int H2 = H >> 1, W2 = W >> 1;
  const int ho = blockIdx.y, n = blockIdx.z;
  const int wo = id >> cshift3, c8 = id & ((1 << cshift3) - 1);
  const bf16* p = in + (((long)(n * H + 2 * ho) * W) + 2 * wo) * C + c8 * 8;
  short8 a = *(const short8*)p;
  short8 bq = *(const short8*)(p + C);
  short8 c = *(const short8*)(p + (long)W * C);
  short8 d = *(const short8*)(p + (long)W * C + C);
  short8 r;
  #pragma unroll
  for (int u = 0; u < 8; ++u) {
    float m = fmaxf(fmaxf(s2f(a[u]), s2f(bq[u])), fmaxf(s2f(c[u]), s2f(d[u])));
    r[u] = f2s(m);
  }
  *(short8*)(out + ((long)(n * H2 + ho) * W2 + wo) * C + c8 * 8) = r;
}

// ---------------------------------------------------------------- FC
__global__ void init_fc(const float* __restrict__ b, float* __restrict__ dst,
                        int fout, int total) {
  int i = blockIdx.x * 256 + threadIdx.x;
  if (i < total) dst[i] = b[i % fout];
}

// FC1: input bf16 NHWC [16,7,7,512], k = c*49 + s remap; k-split partial + atomicAdd
__global__ __launch_bounds__(256) void fc1_partial(
    const bf16* __restrict__ in, const float* __restrict__ w,
    float* __restrict__ outp) {
  const int j = blockIdx.x * 256 + threadIdx.x;
  const int k0 = blockIdx.y * 3136;
  __shared__ float ilds[64][16];
  float acc[16];
  #pragma unroll
  for (int n = 0; n < 16; ++n) acc[n] = 0.f;
  for (int kc = 0; kc < 3136; kc += 64) {
    __syncthreads();
    #pragma unroll
    for (int i = 0; i < 4; ++i) {
      int e = i * 256 + threadIdx.x;
      int kk = e >> 4, n = e & 15;
      int k = k0 + kc + kk;
      int cch = k / 49, s = k - cch * 49;
      ilds[kk][n] = s2f(__builtin_bit_cast(short, in[((long)n * 49 + s) * 512 + cch]));
    }
    __syncthreads();
    #pragma unroll 4
    for (int kk = 0; kk < 64; ++kk) {
      float wv = w[(long)(k0 + kc + kk) * 4096 + j];
      #pragma unroll
      for (int n = 0; n < 16; ++n) acc[n] += ilds[kk][n] * wv;
    }
  }
  #pragma unroll
  for (int n = 0; n < 16; ++n) atomicAdd(&outp[n * 4096 + j], acc[n]);
}

// FC2/FC3: fp32 input with relu-on-read, k-split partial + atomicAdd
__global__ __launch_bounds__(256) void fc_partial(
    const float* __restrict__ in, const float* __restrict__ w,
    float* __restrict__ outp, int fin, int fout, int kPer) {
  const int j = blockIdx.x * 256 + threadIdx.x;
  const int k0 = blockIdx.y * kPer;
  __shared__ float ilds[64][16];
  float acc[16];
  #pragma unroll
  for (int n = 0; n < 16; ++n) acc[n] = 0.f;
  for (int kc = 0; kc < kPer; kc += 64) {
    __syncthreads();
    #pragma unroll
    for (int i = 0; i < 4; ++i) {
      int e = i * 256 + threadIdx.x;
      int kk = e >> 4, n = e & 15;
      ilds[kk][n] = fmaxf(in[(long)n * fin + k0 + kc + kk], 0.f);
    }
    __syncthreads();
    if (j < fout) {
      #pragma unroll 4
      for (int kk = 0; kk < 64; ++kk) {
        float wv = w[(long)(k0 + kc + kk) * fout + j];
        #pragma unroll
        for (int n = 0; n < 16; ++n) acc[n] += ilds[kk][n] * wv;
      }
    }
  }
  if (j < fout) {
    #pragma unroll
    for (int n = 0; n < 16; ++n) atomicAdd(&outp[n * fout + j], acc[n]);
  }
}

// ---------------------------------------------------------------- launch
extern "C" void kernel_launch(void* const* d_in, const int* in_sizes, int n_in,
                              void* d_out, int out_size, void* d_ws, size_t ws_size,
                              hipStream_t stream) {
  const float* x = (const float*)d_in[0];
  const float* cw[13]; const float* cb[13];
  for (int i = 0; i < 13; ++i) { cw[i] = (const float*)d_in[1 + 2 * i]; cb[i] = (const float*)d_in[2 + 2 * i]; }
  const float* fw1 = (const float*)d_in[27]; const float* fb1 = (const float*)d_in[28];
  const float* fw2 = (const float*)d_in[29]; const float* fb2 = (const float*)d_in[30];
  const float* fw3 = (const float*)d_in[31]; const float* fb3 = (const float*)d_in[32];
  float* outp = (float*)d_out;

  const size_t REGION = 102760448;  // 51,380,224 bf16 elems
  char* wsb = (char*)d_ws;
  bf16* A = (bf16*)wsb;
  bf16* B = (bf16*)(wsb + REGION);
  char* ST = wsb + 2 * REGION;
  bf16* zp = (bf16*)ST;                      // 4 KB zero page
  bf16* WB2 = (bf16*)(ST + 4096);            // 73,728 B (L2 weights)
  float* F1 = (float*)(ST + 86016);          // 16x4096 fp32
  float* F2 = F1 + 16 * 4096;
  const size_t WBOFF = 67108864;             // weights at +64MB inside input region

  zerofill<<<4, 256, 0, stream>>>((float*)zp, 1024);

  conv1_first<<<dim3(14, 14, 16), 256, 0, stream>>>(x, cw[0], cb[0], A);

  struct LayerCfg { int cin, cs, cout, H, W; };
  const LayerCfg L[12] = {
      {64, 6, 64, 224, 224},  {64, 6, 128, 112, 112}, {128, 7, 128, 112, 112},
      {128, 7, 256, 56, 56},  {256, 8, 256, 56, 56},  {256, 8, 256, 56, 56},
      {256, 8, 512, 28, 28},  {512, 9, 512, 28, 28},  {512, 9, 512, 28, 28},
      {512, 9, 512, 14, 14},  {512, 9, 512, 14, 14},  {512, 9, 512, 14, 14}};
  // pool after conv index (0-based over L[] which is conv2..conv13): pool1 after L[0], pool2 after L[2], pool3 after L[5], pool4 after L[8], pool5 after L[11]
  const bool poolAfter[12] = {true, false, true, false, false, true, false, false, true, false, false, true};

  bf16* cur = A;
  bf16* oth = B;
  for (int li = 0; li < 12; ++li) {
    const LayerCfg& c = L[li];
    const int K = 9 << c.cs;
    bf16* wb = (li == 0) ? WB2 : (bf16*)((char*)cur + WBOFF);
    repack_w<<<dim3((K + 255) / 256, c.cout), 256, 0, stream>>>(cw[li + 1], wb, c.cin, c.cs, K);
    const int NHW = 16 * c.H * c.W;
    if (c.cout == 64) {
      dim3 g((NHW + 255) / 256, 1);
      conv_gemm<256, 64, 4, 1><<<g, 256, 0, stream>>>(cur, wb, cb[li + 1], oth, zp, c.cin, c.cs, c.cout, c.H, c.W, NHW);
    } else {
      dim3 g((NHW + 127) / 128, c.cout / 128);
      conv_gemm<128, 128, 2, 2><<<g, 256, 0, stream>>>(cur, wb, cb[li + 1], oth, zp, c.cin, c.cs, c.cout, c.H, c.W, NHW);
    }
    bf16* t = cur; cur = oth; oth = t;
    if (poolAfter[li]) {
      int cs3 = (c.cout == 64) ? 3 : (c.cout == 128) ? 4 : (c.cout == 256) ? 5 : 6;
      int W2 = c.W / 2, H2 = c.H / 2;
      int WC8 = W2 << cs3;
      maxpool_nhwc<<<dim3((WC8 + 255) / 256, H2, 16), 256, 0, stream>>>(cur, oth, c.H, c.W, c.cout, cs3, WC8);
      t = cur; cur = oth; oth = t;
    }
  }
  // cur = pool5 output [16,7,7,512] NHWC bf16

  init_fc<<<(16 * 4096 + 255) / 256, 256, 0, stream>>>(fb1, F1, 4096, 16 * 4096);
  fc1_partial<<<dim3(16, 8), 256, 0, stream>>>(cur, fw1, F1);
  init_fc<<<(16 * 4096 + 255) / 256, 256, 0, stream>>>(fb2, F2, 4096, 16 * 4096);
  fc_partial<<<dim3(16, 4), 256, 0, stream>>>(F1, fw2, F2, 4096, 4096, 1024);
  init_fc<<<(16 * 1000 + 255) / 256, 256, 0, stream>>>(fb3, outp, 1000, 16 * 1000);
  fc_partial<<<dim3(4, 4), 256, 0, stream>>>(F2, fw3, outp, 4096, 1000, 1024);
}

// Round 3
// 1468.383 us; speedup vs baseline: 132.1712x; 1.8161x over previous
//
#include <hip/hip_runtime.h>
#include <hip/hip_bf16.h>

typedef __hip_bfloat16 bf16;
typedef __attribute__((ext_vector_type(8))) short short8;
typedef __attribute__((ext_vector_type(8))) __bf16 bf16x8;
typedef __attribute__((ext_vector_type(4))) float f32x4;

__device__ __forceinline__ float s2f(short s) {
  return __builtin_bit_cast(float, (unsigned)((unsigned short)s) << 16);
}
__device__ __forceinline__ short f2s(float f) {
  return __builtin_bit_cast(short, __float2bfloat16(f));
}

__device__ __forceinline__ void gl16(const bf16* g, bf16* l) {
  __builtin_amdgcn_global_load_lds(
      (const __attribute__((address_space(1))) void*)g,
      (__attribute__((address_space(3))) void*)l, 16, 0, 0);
}

// ---------------------------------------------------------------- zero fill (zpage)
__global__ void zerofill(float* p, int n) {
  int i = blockIdx.x * 256 + threadIdx.x;
  if (i < n) p[i] = 0.f;
}

// ---------------------------------------------------------------- layer 1: 3->64, fp32 NCHW in, bf16 NHWC out
__global__ __launch_bounds__(256) void conv1_first(
    const float* __restrict__ x, const float* __restrict__ w,
    const float* __restrict__ b, bf16* __restrict__ out) {
  __shared__ float it[3][18][18];
  __shared__ float wl[1728];
  __shared__ float bl[64];
  const int tid = threadIdx.x;
  const int n = blockIdx.z;
  const int h0 = blockIdx.y * 16, w0 = blockIdx.x * 16;
  for (int i = tid; i < 1728; i += 256) wl[i] = w[i];
  if (tid < 64) bl[tid] = b[tid];
  for (int i = tid; i < 972; i += 256) {
    int ci = i / 324; int r = i - ci * 324; int ty = r / 18, tx = r - ty * 18;
    int hh = h0 - 1 + ty, ww = w0 - 1 + tx;
    float v = 0.f;
    if (hh >= 0 && hh < 224 && ww >= 0 && ww < 224)
      v = x[((long)n * 3 + ci) * 50176 + hh * 224 + ww];
    it[ci][ty][tx] = v;
  }
  __syncthreads();
  const int ty = tid >> 4, tx = tid & 15;
  long ob = (((long)n * 224 + h0 + ty) * 224 + (w0 + tx)) * 64;
  for (int cog = 0; cog < 4; ++cog) {
    float acc[16];
    #pragma unroll
    for (int u = 0; u < 16; ++u) acc[u] = bl[cog * 16 + u];
    #pragma unroll
    for (int ci = 0; ci < 3; ++ci)
      #pragma unroll
      for (int kh = 0; kh < 3; ++kh)
        #pragma unroll
        for (int kw = 0; kw < 3; ++kw) {
          float v = it[ci][ty + kh][tx + kw];
          int jj = ci * 9 + kh * 3 + kw;
          #pragma unroll
          for (int u = 0; u < 16; ++u) acc[u] += v * wl[(cog * 16 + u) * 27 + jj];
        }
    short8 s0, s1;
    #pragma unroll
    for (int u = 0; u < 8; ++u) {
      s0[u] = f2s(fmaxf(acc[u], 0.f));
      s1[u] = f2s(fmaxf(acc[8 + u], 0.f));
    }
    *(short8*)(out + ob + cog * 16) = s0;
    *(short8*)(out + ob + cog * 16 + 8) = s1;
  }
}

// ---------------------------------------------------------------- weight repack: OIHW fp32 -> [Cout][K] bf16, K=(kh*3+kw)*Cin+ci
__global__ void repack_w(const float* __restrict__ w, bf16* __restrict__ wp,
                         int Cin, int cshift, int K) {
  int co = blockIdx.y;
  int k = blockIdx.x * 256 + threadIdx.x;
  if (k < K) {
    int pos = k >> cshift;
    int ci = k & (Cin - 1);
    wp[(long)co * K + k] = __float2bfloat16(w[((long)co * Cin + ci) * 9 + pos]);
  }
}

// ---------------------------------------------------------------- implicit-GEMM conv (NHWC, bf16 MFMA)
// C[p, co] = sum_k A[p,k] * Wp[co,k];  k = pos*Cin + ci, pos=(kh*3+kw)
// per-wave output 64x64; BK=64; XOR-swizzled LDS (both sides, rule #21)
template <int BM, int BN, int WM, int WN>
__global__ __launch_bounds__(WM* WN * 64) void conv_gemm(
    const bf16* __restrict__ in, const bf16* __restrict__ wp,
    const float* __restrict__ bias, bf16* __restrict__ out,
    const bf16* __restrict__ zp,
    int Cin, int cshift, int Cout, int H, int W, int NHW) {
  constexpr int NT = WM * WN * 64;
  constexpr int IA = BM * 8 / NT;   // gload_lds per thread for A tile
  constexpr int IB = BN * 8 / NT;
  __shared__ bf16 lA[BM * 64];
  __shared__ bf16 lB[BN * 64];
  const int tid = threadIdx.x;
  const int lane = tid & 63, wv = tid >> 6;
  const int wr = wv / WN, wc = wv % WN;

  // XCD-aware bijective swizzle (m204): consecutive tiles within one XCD
  const int gx = gridDim.x;
  const int nwg = gx * gridDim.y;
  {
  }
  const int fid = blockIdx.y * gx + blockIdx.x;
  const int q = nwg >> 3, r = nwg & 7;
  const int xcd = fid & 7, idx = fid >> 3;
  const int swz = (xcd < r ? xcd * (q + 1) : r * (q + 1) + (xcd - r) * q) + idx;
  const int p0 = (swz % gx) * BM;
  const int co0 = (swz / gx) * BN;

  const int K = 9 << cshift;
  const int HW = H * W;
  // swizzled k-segment (elements), constant per thread for both A and B staging
  const int colx = ((tid & 7) ^ ((tid >> 3) & 7)) * 8;

  int baseA[IA]; short hA[IA], wA[IA];
  #pragma unroll
  for (int i = 0; i < IA; ++i) {
    int rr = i * (NT / 8) + (tid >> 3);
    int p = p0 + rr;
    if (p < NHW) {
      int n = p / HW; int rem = p - n * HW; int h = rem / W; int w_ = rem - h * W;
      hA[i] = (short)h; wA[i] = (short)w_;
      baseA[i] = ((n * H + h) * W + w_) * Cin;
    } else { hA[i] = -9999; wA[i] = -9999; baseA[i] = 0; }
  }

  f32x4 acc[4][4];
  #pragma unroll
  for (int m = 0; m < 4; ++m)
    #pragma unroll
    for (int n2 = 0; n2 < 4; ++n2) acc[m][n2] = (f32x4){0.f, 0.f, 0.f, 0.f};

  for (int k0 = 0; k0 < K; k0 += 64) {
    const int pos = k0 >> cshift;
    const int dh = pos / 3 - 1, dw = pos % 3 - 1;
    const int ciB = k0 & (Cin - 1);
    const int doff = (dh * W + dw) * Cin + ciB + colx;
    __syncthreads();
    #pragma unroll
    for (int i = 0; i < IA; ++i) {
      int hh = hA[i] + dh, ww = wA[i] + dw;
      bool ok = (hh >= 0) & (hh < H) & (ww >= 0) & (ww < W);
      const bf16* src = ok ? (in + baseA[i] + doff) : zp;
      gl16(src, lA + i * (NT * 8) + wv * 512);
    }
    #pragma unroll
    for (int i = 0; i < IB; ++i) {
      int col = i * (NT / 8) + (tid >> 3);
      const bf16* src = wp + (long)(co0 + col) * K + k0 + colx;
      gl16(src, lB + i * (NT * 8) + wv * 512);
    }
    __syncthreads();
    #pragma unroll
    for (int ks = 0; ks < 2; ++ks) {
      const int kb = ks * 64 + (lane >> 4) * 16;  // byte offset in row
      bf16x8 af[4], bfv[4];
      #pragma unroll
      for (int m = 0; m < 4; ++m) {
        int rr = wr * 64 + m * 16 + (lane & 15);
        af[m] = *(const bf16x8*)((const char*)lA + rr * 128 + (kb ^ ((rr & 7) << 4)));
      }
      #pragma unroll
      for (int n2 = 0; n2 < 4; ++n2) {
        int c = wc * 64 + n2 * 16 + (lane & 15);
        bfv[n2] = *(const bf16x8*)((const char*)lB + c * 128 + (kb ^ ((c & 7) << 4)));
      }
      #pragma unroll
      for (int m = 0; m < 4; ++m)
        #pragma unroll
        for (int n2 = 0; n2 < 4; ++n2)
          acc[m][n2] = __builtin_amdgcn_mfma_f32_16x16x32_bf16(af[m], bfv[n2], acc[m][n2], 0, 0, 0);
    }
  }

  // epilogue: C/D layout col=lane&15, row=(lane>>4)*4+q
  #pragma unroll
  for (int m = 0; m < 4; ++m) {
    int pb = p0 + wr * 64 + m * 16 + (lane >> 4) * 4;
    #pragma unroll
    for (int n2 = 0; n2 < 4; ++n2) {
      int co = co0 + wc * 64 + n2 * 16 + (lane & 15);
      float bb = bias[co];
      #pragma unroll
      for (int qq = 0; qq < 4; ++qq) {
        int pp = pb + qq;
        if (pp < NHW)
          out[(long)pp * Cout + co] = __float2bfloat16(fmaxf(acc[m][n2][qq] + bb, 0.f));
      }
    }
  }
}

// ---------------------------------------------------------------- maxpool 2x2 NHWC (short8 vectors)
__global__ void maxpool_nhwc(const bf16* __restrict__ in, bf16* __restrict__ out,
                             int H, int W, int C, int cshift3, int WC8) {
  const int id = blockIdx.x * 256 + threadIdx.x;
  if (id >= WC8) return;
  const int H2 = H >> 1, W2 = W >> 1;
  const int ho = blockIdx.y, n = blockIdx.z;
  const int wo = id >> cshift3, c8 = id & ((1 << cshift3) - 1);
  const bf16* p = in + (((long)(n * H + 2 * ho) * W) + 2 * wo) * C + c8 * 8;
  short8 a = *(const short8*)p;
  short8 bq = *(const short8*)(p + C);
  short8 c = *(const short8*)(p + (long)W * C);
  short8 d = *(const short8*)(p + (long)W * C + C);
  short8 r;
  #pragma unroll
  for (int u = 0; u < 8; ++u) {
    float m = fmaxf(fmaxf(s2f(a[u]), s2f(bq[u])), fmaxf(s2f(c[u]), s2f(d[u])));
    r[u] = f2s(m);
  }
  *(short8*)(out + ((long)(n * H2 + ho) * W2 + wo) * C + c8 * 8) = r;
}

// ---------------------------------------------------------------- FC1 partial
// in: bf16 NHWC [16,7,7,512]; k = c*49 + s;  grid (4, 98), kPer=256
// part[by][n][j] = sum_{k in chunk} in[n,k] * w[k,j]
__global__ __launch_bounds__(256) void fc1_partial(
    const bf16* __restrict__ in, const float* __restrict__ w,
    float* __restrict__ part) {
  const int j0 = blockIdx.x * 1024 + threadIdx.x * 4;
  const int k0 = blockIdx.y * 256;
  __shared__ float ilds[256][16];
  #pragma unroll
  for (int i = 0; i < 16; ++i) {
    int e = i * 256 + threadIdx.x;
    int kk = e >> 4, n = e & 15;
    int k = k0 + kk;
    int cch = k / 49, s = k - cch * 49;
    ilds[kk][n] = s2f(__builtin_bit_cast(short, in[((long)n * 49 + s) * 512 + cch]));
  }
  __syncthreads();
  f32x4 acc[16];
  #pragma unroll
  for (int n = 0; n < 16; ++n) acc[n] = (f32x4){0.f, 0.f, 0.f, 0.f};
  #pragma unroll 4
  for (int kk = 0; kk < 256; ++kk) {
    f32x4 w4 = *(const f32x4*)(w + (long)(k0 + kk) * 4096 + j0);
    #pragma unroll
    for (int n = 0; n < 16; ++n) {
      float v = ilds[kk][n];
      acc[n] += v * w4;
    }
  }
  float* pp = part + (long)blockIdx.y * 16 * 4096;
  #pragma unroll
  for (int n = 0; n < 16; ++n) *(f32x4*)(pp + n * 4096 + j0) = acc[n];
}

// ---------------------------------------------------------------- FC2/FC3 partial (fp32 in, relu-on-read)
// grid (gx, 64), chunk of 64 k per block
__global__ __launch_bounds__(256) void fc23_partial(
    const float* __restrict__ in, const float* __restrict__ w,
    float* __restrict__ part, int fin, int fout) {
  const int j0 = blockIdx.x * 1024 + threadIdx.x * 4;
  const int k0 = blockIdx.y * 64;
  __shared__ float ilds[64][16];
  #pragma unroll
  for (int i = 0; i < 4; ++i) {
    int e = i * 256 + threadIdx.x;
    int kk = e >> 4, n = e & 15;
    ilds[kk][n] = fmaxf(in[(long)n * fin + k0 + kk], 0.f);
  }
  __syncthreads();
  if (j0 >= fout) return;
  f32x4 acc[16];
  #pragma unroll
  for (int n = 0; n < 16; ++n) acc[n] = (f32x4){0.f, 0.f, 0.f, 0.f};
  #pragma unroll 4
  for (int kk = 0; kk < 64; ++kk) {
    f32x4 w4 = *(const f32x4*)(w + (long)(k0 + kk) * fout + j0);
    #pragma unroll
    for (int n = 0; n < 16; ++n) {
      float v = ilds[kk][n];
      acc[n] += v * w4;
    }
  }
  float* pp = part + (long)blockIdx.y * 16 * fout;
  #pragma unroll
  for (int n = 0; n < 16; ++n) *(f32x4*)(pp + n * fout + j0) = acc[n];
}

// ---------------------------------------------------------------- reduce partials + bias (no relu; consumer applies)
__global__ void reduce_fc(const float* __restrict__ part, const float* __restrict__ bias,
                          float* __restrict__ out, int nparts, int fout, int total) {
  int i = blockIdx.x * 256 + threadIdx.x;
  if (i >= total) return;
  int n = i / fout, j = i - n * fout;
  float s = bias[j];
  for (int p = 0; p < nparts; ++p) s += part[((long)p * 16 + n) * fout + j];
  out[i] = s;
}

// ---------------------------------------------------------------- launch
extern "C" void kernel_launch(void* const* d_in, const int* in_sizes, int n_in,
                              void* d_out, int out_size, void* d_ws, size_t ws_size,
                              hipStream_t stream) {
  const float* x = (const float*)d_in[0];
  const float* cw[13]; const float* cb[13];
  for (int i = 0; i < 13; ++i) { cw[i] = (const float*)d_in[1 + 2 * i]; cb[i] = (const float*)d_in[2 + 2 * i]; }
  const float* fw1 = (const float*)d_in[27]; const float* fb1 = (const float*)d_in[28];
  const float* fw2 = (const float*)d_in[29]; const float* fb2 = (const float*)d_in[30];
  const float* fw3 = (const float*)d_in[31]; const float* fb3 = (const float*)d_in[32];
  float* outp = (float*)d_out;

  const size_t REGION = 102760448;  // 51,380,224 bf16 elems
  char* wsb = (char*)d_ws;
  bf16* A = (bf16*)wsb;
  bf16* B = (bf16*)(wsb + REGION);
  char* ST = wsb + 2 * REGION;
  bf16* zp = (bf16*)ST;                      // 4 KB zero page
  bf16* WB2 = (bf16*)(ST + 4096);            // 73,728 B (L2 weights)
  float* F1 = (float*)(ST + 86016);          // 16x4096 fp32
  float* F2 = F1 + 16 * 4096;
  const size_t WBOFF = 67108864;             // weights at +64MB inside input region

  zerofill<<<4, 256, 0, stream>>>((float*)zp, 1024);

  conv1_first<<<dim3(14, 14, 16), 256, 0, stream>>>(x, cw[0], cb[0], A);

  struct LayerCfg { int cin, cs, cout, H, W; };
  const LayerCfg L[12] = {
      {64, 6, 64, 224, 224},  {64, 6, 128, 112, 112}, {128, 7, 128, 112, 112},
      {128, 7, 256, 56, 56},  {256, 8, 256, 56, 56},  {256, 8, 256, 56, 56},
      {256, 8, 512, 28, 28},  {512, 9, 512, 28, 28},  {512, 9, 512, 28, 28},
      {512, 9, 512, 14, 14},  {512, 9, 512, 14, 14},  {512, 9, 512, 14, 14}};
  const bool poolAfter[12] = {true, false, true, false, false, true, false, false, true, false, false, true};

  bf16* cur = A;
  bf16* oth = B;
  for (int li = 0; li < 12; ++li) {
    const LayerCfg& c = L[li];
    const int K = 9 << c.cs;
    bf16* wb = (li == 0) ? WB2 : (bf16*)((char*)cur + WBOFF);
    repack_w<<<dim3((K + 255) / 256, c.cout), 256, 0, stream>>>(cw[li + 1], wb, c.cin, c.cs, K);
    const int NHW = 16 * c.H * c.W;
    if (li == 0) {
      // 64 output channels, huge M
      conv_gemm<256, 64, 4, 1><<<dim3(NHW / 256, 1), 256, 0, stream>>>(
          cur, wb, cb[li + 1], oth, zp, c.cin, c.cs, c.cout, c.H, c.W, NHW);
    } else if (li >= 3 && li <= 5) {
      // 56x56, Cout=256: 8-wave 128x256 tile (halves A traffic), 392 blocks
      conv_gemm<128, 256, 2, 4><<<dim3(NHW / 128, c.cout / 256), 512, 0, stream>>>(
          cur, wb, cb[li + 1], oth, zp, c.cin, c.cs, c.cout, c.H, c.W, NHW);
    } else {
      conv_gemm<128, 128, 2, 2><<<dim3((NHW + 127) / 128, c.cout / 128), 256, 0, stream>>>(
          cur, wb, cb[li + 1], oth, zp, c.cin, c.cs, c.cout, c.H, c.W, NHW);
    }
    bf16* t = cur; cur = oth; oth = t;
    if (poolAfter[li]) {
      int cs3 = (c.cout == 64) ? 3 : (c.cout == 128) ? 4 : (c.cout == 256) ? 5 : 6;
      int W2 = c.W / 2, H2 = c.H / 2;
      int WC8 = W2 << cs3;
      maxpool_nhwc<<<dim3((WC8 + 255) / 256, H2, 16), 256, 0, stream>>>(cur, oth, c.H, c.W, c.cout, cs3, WC8);
      t = cur; cur = oth; oth = t;
    }
  }
  // cur = pool5 output [16,7,7,512] NHWC bf16, lives in region B.
  // Region A is free during the FC phase -> partial buffers overlay it.
  float* P1 = (float*)A;                                  // 98*16*4096*4 = 25.7 MB
  float* P2 = (float*)((char*)A + 32u * 1024 * 1024);     // 64*16*4096*4 = 16.8 MB
  float* P3 = (float*)((char*)A + 52u * 1024 * 1024);     // 64*16*1000*4 =  4.1 MB

  fc1_partial<<<dim3(4, 98), 256, 0, stream>>>(cur, fw1, P1);
  reduce_fc<<<(16 * 4096 + 255) / 256, 256, 0, stream>>>(P1, fb1, F1, 98, 4096, 16 * 4096);
  fc23_partial<<<dim3(4, 64), 256, 0, stream>>>(F1, fw2, P2, 4096, 4096);
  reduce_fc<<<(16 * 4096 + 255) / 256, 256, 0, stream>>>(P2, fb2, F2, 64, 4096, 16 * 4096);
  fc23_partial<<<dim3(1, 64), 256, 0, stream>>>(F2, fw3, P3, 4096, 1000);
  reduce_fc<<<(16 * 1000 + 255) / 256, 256, 0, stream>>>(P3, fb3, outp, 64, 1000, 16 * 1000);
}

// Round 5
// 1357.616 us; speedup vs baseline: 142.9550x; 1.0816x over previous
//
#include <hip/hip_runtime.h>
#include <hip/hip_bf16.h>

typedef __hip_bfloat16 bf16;
typedef __attribute__((ext_vector_type(4))) short s16x4;
typedef __attribute__((ext_vector_type(8))) short short8;
typedef __attribute__((ext_vector_type(8))) __bf16 bf16x8;
typedef __attribute__((ext_vector_type(4))) float f32x4;

__device__ __forceinline__ float s2f(short s) {
  return __builtin_bit_cast(float, (unsigned)((unsigned short)s) << 16);
}
__device__ __forceinline__ short f2s(float f) {
  return __builtin_bit_cast(short, __float2bfloat16(f));
}

__device__ __forceinline__ void gl16(const bf16* g, bf16* l) {
  __builtin_amdgcn_global_load_lds(
      (const __attribute__((address_space(1))) void*)g,
      (__attribute__((address_space(3))) void*)l, 16, 0, 0);
}

// ---------------------------------------------------------------- zero fill (zpage)
__global__ void zerofill(float* p, int n) {
  int i = blockIdx.x * 256 + threadIdx.x;
  if (i < n) p[i] = 0.f;
}

// ---------------------------------------------------------------- layer 1: 3->64, fp32 NCHW in, bf16 NHWC out
__global__ __launch_bounds__(256) void conv1_first(
    const float* __restrict__ x, const float* __restrict__ w,
    const float* __restrict__ b, bf16* __restrict__ out) {
  __shared__ float it[3][18][18];
  __shared__ float wl[1728];
  __shared__ float bl[64];
  const int tid = threadIdx.x;
  const int n = blockIdx.z;
  const int h0 = blockIdx.y * 16, w0 = blockIdx.x * 16;
  for (int i = tid; i < 1728; i += 256) wl[i] = w[i];
  if (tid < 64) bl[tid] = b[tid];
  for (int i = tid; i < 972; i += 256) {
    int ci = i / 324; int r = i - ci * 324; int ty = r / 18, tx = r - ty * 18;
    int hh = h0 - 1 + ty, ww = w0 - 1 + tx;
    float v = 0.f;
    if (hh >= 0 && hh < 224 && ww >= 0 && ww < 224)
      v = x[((long)n * 3 + ci) * 50176 + hh * 224 + ww];
    it[ci][ty][tx] = v;
  }
  __syncthreads();
  const int ty = tid >> 4, tx = tid & 15;
  long ob = (((long)n * 224 + h0 + ty) * 224 + (w0 + tx)) * 64;
  for (int cog = 0; cog < 4; ++cog) {
    float acc[16];
    #pragma unroll
    for (int u = 0; u < 16; ++u) acc[u] = bl[cog * 16 + u];
    #pragma unroll
    for (int ci = 0; ci < 3; ++ci)
      #pragma unroll
      for (int kh = 0; kh < 3; ++kh)
        #pragma unroll
        for (int kw = 0; kw < 3; ++kw) {
          float v = it[ci][ty + kh][tx + kw];
          int jj = ci * 9 + kh * 3 + kw;
          #pragma unroll
          for (int u = 0; u < 16; ++u) acc[u] += v * wl[(cog * 16 + u) * 27 + jj];
        }
    short8 s0, s1;
    #pragma unroll
    for (int u = 0; u < 8; ++u) {
      s0[u] = f2s(fmaxf(acc[u], 0.f));
      s1[u] = f2s(fmaxf(acc[8 + u], 0.f));
    }
    *(short8*)(out + ob + cog * 16) = s0;
    *(short8*)(out + ob + cog * 16 + 8) = s1;
  }
}

// ---------------------------------------------------------------- fused weight repack (all 12 MFMA conv layers)
// OIHW fp32 -> [Cout][K] bf16, K=(kh*3+kw)*Cin+ci. One block per (co, layer).
struct RepackMeta {
  const float* src[12];
  long dstOff[12];
  int cinM1[12];
  int cshift[12];
  int cout[12];
};

__global__ __launch_bounds__(256) void repack_all(RepackMeta m, bf16* __restrict__ blob) {
  const int li = blockIdx.y;
  const int co = blockIdx.x;
  if (co >= m.cout[li]) return;
  const int cs = m.cshift[li];
  const int cinM1 = m.cinM1[li];
  const int K = 9 << cs;
  const float* src = m.src[li] + (long)co * (cinM1 + 1) * 9;
  bf16* dst = blob + m.dstOff[li] + (long)co * K;
  for (int k = threadIdx.x; k < K; k += 256) {
    int pos = k >> cs;
    int ci = k & cinM1;
    dst[k] = __float2bfloat16(src[ci * 9 + pos]);
  }
}

// ---------------------------------------------------------------- implicit-GEMM conv (NHWC, bf16 MFMA)
// C[p, co] = sum_k A[p,k] * Wp[co,k];  k = pos*Cin + ci, pos=(kh*3+kw)
// XOR-swizzled LDS (both sides, rule #21); optional split-K (fp32 partials)
template <int BM, int BN, int WM, int WN, int SPLITK>
__global__ __launch_bounds__(WM* WN * 64) void conv_gemm(
    const bf16* __restrict__ in, const bf16* __restrict__ wp,
    const float* __restrict__ bias, bf16* __restrict__ out,
    float* __restrict__ pout, const bf16* __restrict__ zp,
    int Cin, int cshift, int Cout, int H, int W, int NHW) {
  constexpr int NT = WM * WN * 64;
  constexpr int IA = BM * 8 / NT;   // gload_lds per thread for A tile
  constexpr int IB = BN * 8 / NT;
  __shared__ bf16 lA[BM * 64];
  __shared__ bf16 lB[BN * 64];
  const int tid = threadIdx.x;
  const int lane = tid & 63, wv = tid >> 6;
  const int wr = wv / WN, wc = wv % WN;

  // XCD-aware bijective swizzle (m204) over the x*y grid (independent per z)
  const int gx = gridDim.x;
  const int nwg = gx * gridDim.y;
  const int fid = blockIdx.y * gx + blockIdx.x;
  const int q = nwg >> 3, r = nwg & 7;
  const int xcd = fid & 7, idx = fid >> 3;
  const int swz = (xcd < r ? xcd * (q + 1) : r * (q + 1) + (xcd - r) * q) + idx;
  const int p0 = (swz % gx) * BM;
  const int co0 = (swz / gx) * BN;

  const int K = 9 << cshift;
  const int HW = H * W;
  const int colx = ((tid & 7) ^ ((tid >> 3) & 7)) * 8;

  int baseA[IA]; short hA[IA], wA[IA];
  #pragma unroll
  for (int i = 0; i < IA; ++i) {
    int rr = i * (NT / 8) + (tid >> 3);
    int p = p0 + rr;
    if (p < NHW) {
      int n = p / HW; int rem = p - n * HW; int h = rem / W; int w_ = rem - h * W;
      hA[i] = (short)h; wA[i] = (short)w_;
      baseA[i] = ((n * H + h) * W + w_) * Cin;
    } else { hA[i] = -9999; wA[i] = -9999; baseA[i] = 0; }
  }

  f32x4 acc[4][4];
  #pragma unroll
  for (int m = 0; m < 4; ++m)
    #pragma unroll
    for (int n2 = 0; n2 < 4; ++n2) acc[m][n2] = (f32x4){0.f, 0.f, 0.f, 0.f};

  const int Kper = K / SPLITK;
  const int kBeg = (SPLITK > 1) ? (int)blockIdx.z * Kper : 0;
  for (int k0 = kBeg; k0 < kBeg + Kper; k0 += 64) {
    const int pos = k0 >> cshift;
    const int dh = pos / 3 - 1, dw = pos % 3 - 1;
    const int ciB = k0 & (Cin - 1);
    const int doff = (dh * W + dw) * Cin + ciB + colx;
    __syncthreads();
    #pragma unroll
    for (int i = 0; i < IA; ++i) {
      int hh = hA[i] + dh, ww = wA[i] + dw;
      bool ok = (hh >= 0) & (hh < H) & (ww >= 0) & (ww < W);
      const bf16* src = ok ? (in + baseA[i] + doff) : zp;
      gl16(src, lA + i * (NT * 8) + wv * 512);
    }
    #pragma unroll
    for (int i = 0; i < IB; ++i) {
      int col = i * (NT / 8) + (tid >> 3);
      const bf16* src = wp + (long)(co0 + col) * K + k0 + colx;
      gl16(src, lB + i * (NT * 8) + wv * 512);
    }
    __syncthreads();
    #pragma unroll
    for (int ks = 0; ks < 2; ++ks) {
      const int kb = ks * 64 + (lane >> 4) * 16;  // byte offset in row
      bf16x8 af[4], bfv[4];
      #pragma unroll
      for (int m = 0; m < 4; ++m) {
        int rr = wr * 64 + m * 16 + (lane & 15);
        af[m] = *(const bf16x8*)((const char*)lA + rr * 128 + (kb ^ ((rr & 7) << 4)));
      }
      #pragma unroll
      for (int n2 = 0; n2 < 4; ++n2) {
        int c = wc * 64 + n2 * 16 + (lane & 15);
        bfv[n2] = *(const bf16x8*)((const char*)lB + c * 128 + (kb ^ ((c & 7) << 4)));
      }
      #pragma unroll
      for (int m = 0; m < 4; ++m)
        #pragma unroll
        for (int n2 = 0; n2 < 4; ++n2)
          acc[m][n2] = __builtin_amdgcn_mfma_f32_16x16x32_bf16(af[m], bfv[n2], acc[m][n2], 0, 0, 0);
    }
  }

  // epilogue: C/D layout col=lane&15, row=(lane>>4)*4+q
  if constexpr (SPLITK == 1) {
    #pragma unroll
    for (int m = 0; m < 4; ++m) {
      int pb = p0 + wr * 64 + m * 16 + (lane >> 4) * 4;
      #pragma unroll
      for (int n2 = 0; n2 < 4; ++n2) {
        int co = co0 + wc * 64 + n2 * 16 + (lane & 15);
        float bb = bias[co];
        #pragma unroll
        for (int qq = 0; qq < 4; ++qq) {
          int pp = pb + qq;
          if (pp < NHW)
            out[(long)pp * Cout + co] = __float2bfloat16(fmaxf(acc[m][n2][qq] + bb, 0.f));
        }
      }
    }
  } else {
    float* pb_ = pout + (long)blockIdx.z * NHW * Cout;
    #pragma unroll
    for (int m = 0; m < 4; ++m) {
      int pb = p0 + wr * 64 + m * 16 + (lane >> 4) * 4;
      #pragma unroll
      for (int n2 = 0; n2 < 4; ++n2) {
        int co = co0 + wc * 64 + n2 * 16 + (lane & 15);
        #pragma unroll
        for (int qq = 0; qq < 4; ++qq) {
          int pp = pb + qq;
          if (pp < NHW) pb_[(long)pp * Cout + co] = acc[m][n2][qq];
        }
      }
    }
  }
}

// ---------------------------------------------------------------- split-K reduce: part0+part1+bias, relu, ->bf16
__global__ __launch_bounds__(256) void reduce_split(
    const float* __restrict__ part, const float* __restrict__ bias,
    bf16* __restrict__ out, int NHW, int Cout) {
  long e4 = ((long)blockIdx.x * 256 + threadIdx.x) * 4;
  long total = (long)NHW * Cout;
  if (e4 >= total) return;
  f32x4 a = *(const f32x4*)(part + e4);
  f32x4 b = *(const f32x4*)(part + total + e4);
  f32x4 bv = *(const f32x4*)(bias + (int)(e4 & (Cout - 1)));
  s16x4 r;
  #pragma unroll
  for (int u = 0; u < 4; ++u) r[u] = f2s(fmaxf(a[u] + b[u] + bv[u], 0.f));
  *(s16x4*)(out + e4) = r;
}

// ---------------------------------------------------------------- maxpool 2x2 NHWC (short8 vectors)
__global__ void maxpool_nhwc(const bf16* __restrict__ in, bf16* __restrict__ out,
                             int H, int W, int C, int cshift3, int WC8) {
  const int id = blockIdx.x * 256 + threadIdx.x;
  if (id >= WC8) return;
  const int H2 = H >> 1, W2 = W >> 1;
  const int ho = blockIdx.y, n = blockIdx.z;
  const int wo = id >> cshift3, c8 = id & ((1 << cshift3) - 1);
  const bf16* p = in + (((long)(n * H + 2 * ho) * W) + 2 * wo) * C + c8 * 8;
  short8 a = *(const short8*)p;
  short8 bq = *(const short8*)(p + C);
  short8 c = *(const short8*)(p + (long)W * C);
  short8 d = *(const short8*)(p + (long)W * C + C);
  short8 r;
  #pragma unroll
  for (int u = 0; u < 8; ++u) {
    float m = fmaxf(fmaxf(s2f(a[u]), s2f(bq[u])), fmaxf(s2f(c[u]), s2f(d[u])));
    r[u] = f2s(m);
  }
  *(short8*)(out + ((long)(n * H2 + ho) * W2 + wo) * C + c8 * 8) = r;
}

// ---------------------------------------------------------------- FC1 partial
__global__ __launch_bounds__(256) void fc1_partial(
    const bf16* __restrict__ in, const float* __restrict__ w,
    float* __restrict__ part) {
  const int j0 = blockIdx.x * 1024 + threadIdx.x * 4;
  const int k0 = blockIdx.y * 256;
  __shared__ float ilds[256][16];
  #pragma unroll
  for (int i = 0; i < 16; ++i) {
    int e = i * 256 + threadIdx.x;
    int kk = e >> 4, n = e & 15;
    int k = k0 + kk;
    int cch = k / 49, s = k - cch * 49;
    ilds[kk][n] = s2f(__builtin_bit_cast(short, in[((long)n * 49 + s) * 512 + cch]));
  }
  __syncthreads();
  f32x4 acc[16];
  #pragma unroll
  for (int n = 0; n < 16; ++n) acc[n] = (f32x4){0.f, 0.f, 0.f, 0.f};
  #pragma unroll 4
  for (int kk = 0; kk < 256; ++kk) {
    f32x4 w4 = *(const f32x4*)(w + (long)(k0 + kk) * 4096 + j0);
    #pragma unroll
    for (int n = 0; n < 16; ++n) {
      float v = ilds[kk][n];
      acc[n] += v * w4;
    }
  }
  float* pp = part + (long)blockIdx.y * 16 * 4096;
  #pragma unroll
  for (int n = 0; n < 16; ++n) *(f32x4*)(pp + n * 4096 + j0) = acc[n];
}

// ---------------------------------------------------------------- FC2/FC3 partial (fp32 in, relu-on-read)
__global__ __launch_bounds__(256) void fc23_partial(
    const float* __restrict__ in, const float* __restrict__ w,
    float* __restrict__ part, int fin, int fout) {
  const int j0 = blockIdx.x * 1024 + threadIdx.x * 4;
  const int k0 = blockIdx.y * 64;
  __shared__ float ilds[64][16];
  #pragma unroll
  for (int i = 0; i < 4; ++i) {
    int e = i * 256 + threadIdx.x;
    int kk = e >> 4, n = e & 15;
    ilds[kk][n] = fmaxf(in[(long)n * fin + k0 + kk], 0.f);
  }
  __syncthreads();
  if (j0 >= fout) return;
  f32x4 acc[16];
  #pragma unroll
  for (int n = 0; n < 16; ++n) acc[n] = (f32x4){0.f, 0.f, 0.f, 0.f};
  #pragma unroll 4
  for (int kk = 0; kk < 64; ++kk) {
    f32x4 w4 = *(const f32x4*)(w + (long)(k0 + kk) * fout + j0);
    #pragma unroll
    for (int n = 0; n < 16; ++n) {
      float v = ilds[kk][n];
      acc[n] += v * w4;
    }
  }
  float* pp = part + (long)blockIdx.y * 16 * fout;
  #pragma unroll
  for (int n = 0; n < 16; ++n) *(f32x4*)(pp + n * fout + j0) = acc[n];
}

// ---------------------------------------------------------------- reduce FC partials + bias
__global__ void reduce_fc(const float* __restrict__ part, const float* __restrict__ bias,
                          float* __restrict__ out, int nparts, int fout, int total) {
  int i = blockIdx.x * 256 + threadIdx.x;
  if (i >= total) return;
  int n = i / fout, j = i - n * fout;
  float s = bias[j];
  for (int p = 0; p < nparts; ++p) s += part[((long)p * 16 + n) * fout + j];
  out[i] = s;
}

// ---------------------------------------------------------------- launch
extern "C" void kernel_launch(void* const* d_in, const int* in_sizes, int n_in,
                              void* d_out, int out_size, void* d_ws, size_t ws_size,
                              hipStream_t stream) {
  const float* x = (const float*)d_in[0];
  const float* cw[13]; const float* cb[13];
  for (int i = 0; i < 13; ++i) { cw[i] = (const float*)d_in[1 + 2 * i]; cb[i] = (const float*)d_in[2 + 2 * i]; }
  const float* fw1 = (const float*)d_in[27]; const float* fb1 = (const float*)d_in[28];
  const float* fw2 = (const float*)d_in[29]; const float* fb2 = (const float*)d_in[30];
  const float* fw3 = (const float*)d_in[31]; const float* fb3 = (const float*)d_in[32];
  float* outp = (float*)d_out;

  const size_t REGION = 102760448;  // 51,380,224 bf16 elems
  char* wsb = (char*)d_ws;
  bf16* A = (bf16*)wsb;
  bf16* B = (bf16*)(wsb + REGION);
  char* ST = wsb + 2 * REGION;
  bf16* zp = (bf16*)ST;                          // 4 KB zero page
  bf16* WBLOB = (bf16*)(ST + 4096);              // ~29.4 MB repacked weights
  char* ST2 = ST + 4096 + 31 * 1024 * 1024;
  float* F1 = (float*)ST2;                       // 16x4096 fp32
  float* F2 = F1 + 16 * 4096;
  float* PS = F2 + 16 * 4096;                    // split-K partials: 2*3136*512 fp32 = 12.85 MB

  struct LayerCfg { int cin, cs, cout, H, W; };
  const LayerCfg L[12] = {
      {64, 6, 64, 224, 224},  {64, 6, 128, 112, 112}, {128, 7, 128, 112, 112},
      {128, 7, 256, 56, 56},  {256, 8, 256, 56, 56},  {256, 8, 256, 56, 56},
      {256, 8, 512, 28, 28},  {512, 9, 512, 28, 28},  {512, 9, 512, 28, 28},
      {512, 9, 512, 14, 14},  {512, 9, 512, 14, 14},  {512, 9, 512, 14, 14}};
  const bool poolAfter[12] = {true, false, true, false, false, true, false, false, true, false, false, true};

  // ---- fused weight repack
  RepackMeta rm;
  long off = 0;
  long offs[12];
  for (int li = 0; li < 12; ++li) {
    rm.src[li] = cw[li + 1];
    rm.cinM1[li] = L[li].cin - 1;
    rm.cshift[li] = L[li].cs;
    rm.cout[li] = L[li].cout;
    rm.dstOff[li] = off;
    offs[li] = off;
    off += (long)L[li].cout * (9 << L[li].cs);
  }
  zerofill<<<4, 256, 0, stream>>>((float*)zp, 1024);
  repack_all<<<dim3(512, 12), 256, 0, stream>>>(rm, WBLOB);

  conv1_first<<<dim3(14, 14, 16), 256, 0, stream>>>(x, cw[0], cb[0], A);

  bf16* cur = A;
  bf16* oth = B;
  for (int li = 0; li < 12; ++li) {
    const LayerCfg& c = L[li];
    bf16* wb = WBLOB + offs[li];
    const int NHW = 16 * c.H * c.W;
    if (li == 0) {
      // 224x224, N=64: 3136 WGs, 4-wave
      conv_gemm<256, 64, 4, 1, 1><<<dim3(NHW / 256, 1), 256, 0, stream>>>(
          cur, wb, cb[li + 1], oth, nullptr, zp, c.cin, c.cs, c.cout, c.H, c.W, NHW);
    } else if (li <= 2) {
      // 112x112, N=128: 784 WGs, 8-wave big-M tile
      conv_gemm<256, 128, 4, 2, 1><<<dim3(NHW / 256, 1), 512, 0, stream>>>(
          cur, wb, cb[li + 1], oth, nullptr, zp, c.cin, c.cs, c.cout, c.H, c.W, NHW);
    } else if (li <= 5) {
      // 56x56, N=256: 392 WGs, 8-wave wide-N tile
      conv_gemm<128, 256, 2, 4, 1><<<dim3(NHW / 128, 1), 512, 0, stream>>>(
          cur, wb, cb[li + 1], oth, nullptr, zp, c.cin, c.cs, c.cout, c.H, c.W, NHW);
    } else if (li <= 8) {
      // 28x28, N=512: 392 WGs, 4-wave
      conv_gemm<128, 128, 2, 2, 1><<<dim3((NHW + 127) / 128, c.cout / 128), 256, 0, stream>>>(
          cur, wb, cb[li + 1], oth, nullptr, zp, c.cin, c.cs, c.cout, c.H, c.W, NHW);
    } else {
      // 14x14, N=512: split-K=2 -> 200 WGs + deterministic reduce
      conv_gemm<128, 128, 2, 2, 2><<<dim3((NHW + 127) / 128, c.cout / 128, 2), 256, 0, stream>>>(
          cur, wb, cb[li + 1], nullptr, PS, zp, c.cin, c.cs, c.cout, c.H, c.W, NHW);
      long tot = (long)NHW * c.cout;
      reduce_split<<<(int)((tot / 4 + 255) / 256), 256, 0, stream>>>(PS, cb[li + 1], oth, NHW, c.cout);
    }
    bf16* t = cur; cur = oth; oth = t;
    if (poolAfter[li]) {
      int cs3 = (c.cout == 64) ? 3 : (c.cout == 128) ? 4 : (c.cout == 256) ? 5 : 6;
      int W2 = c.W / 2, H2 = c.H / 2;
      int WC8 = W2 << cs3;
      maxpool_nhwc<<<dim3((WC8 + 255) / 256, H2, 16), 256, 0, stream>>>(cur, oth, c.H, c.W, c.cout, cs3, WC8);
      t = cur; cur = oth; oth = t;
    }
  }
  // cur = pool5 output [16,7,7,512] NHWC bf16, lives in region B.
  // Region A is free during the FC phase -> partial buffers overlay it.
  float* P1 = (float*)A;                                  // 98*16*4096*4 = 25.7 MB
  float* P2 = (float*)((char*)A + 32u * 1024 * 1024);     // 64*16*4096*4 = 16.8 MB
  float* P3 = (float*)((char*)A + 52u * 1024 * 1024);     // 64*16*1000*4 =  4.1 MB

  fc1_partial<<<dim3(4, 98), 256, 0, stream>>>(cur, fw1, P1);
  reduce_fc<<<(16 * 4096 + 255) / 256, 256, 0, stream>>>(P1, fb1, F1, 98, 4096, 16 * 4096);
  fc23_partial<<<dim3(4, 64), 256, 0, stream>>>(F1, fw2, P2, 4096, 4096);
  reduce_fc<<<(16 * 4096 + 255) / 256, 256, 0, stream>>>(P2, fb2, F2, 64, 4096, 16 * 4096);
  fc23_partial<<<dim3(1, 64), 256, 0, stream>>>(F2, fw3, P3, 4096, 1000);
  reduce_fc<<<(16 * 1000 + 255) / 256, 256, 0, stream>>>(P3, fb3, outp, 64, 1000, 16 * 1000);
}

// Round 6
// 1278.018 us; speedup vs baseline: 151.8585x; 1.0623x over previous
//
#include <hip/hip_runtime.h>
#include <hip/hip_bf16.h>

typedef __hip_bfloat16 bf16;
typedef __attribute__((ext_vector_type(4))) short s16x4;
typedef __attribute__((ext_vector_type(8))) short short8;
typedef __attribute__((ext_vector_type(8))) __bf16 bf16x8;
typedef __attribute__((ext_vector_type(4))) float f32x4;

__device__ __forceinline__ float s2f(short s) {
  return __builtin_bit_cast(float, (unsigned)((unsigned short)s) << 16);
}
__device__ __forceinline__ short f2s(float f) {
  return __builtin_bit_cast(short, __float2bfloat16(f));
}

__device__ __forceinline__ void gl16(const bf16* g, bf16* l) {
  __builtin_amdgcn_global_load_lds(
      (const __attribute__((address_space(1))) void*)g,
      (__attribute__((address_space(3))) void*)l, 16, 0, 0);
}

// ---------------------------------------------------------------- zero fill (zpage)
__global__ void zerofill(float* p, int n) {
  int i = blockIdx.x * 256 + threadIdx.x;
  if (i < n) p[i] = 0.f;
}

// ---------------------------------------------------------------- layer 1: 3->64, fp32 NCHW in, bf16 NHWC out
__global__ __launch_bounds__(256) void conv1_first(
    const float* __restrict__ x, const float* __restrict__ w,
    const float* __restrict__ b, bf16* __restrict__ out) {
  __shared__ float it[3][18][18];
  __shared__ float wl[1728];
  __shared__ float bl[64];
  const int tid = threadIdx.x;
  const int n = blockIdx.z;
  const int h0 = blockIdx.y * 16, w0 = blockIdx.x * 16;
  for (int i = tid; i < 1728; i += 256) wl[i] = w[i];
  if (tid < 64) bl[tid] = b[tid];
  for (int i = tid; i < 972; i += 256) {
    int ci = i / 324; int r = i - ci * 324; int ty = r / 18, tx = r - ty * 18;
    int hh = h0 - 1 + ty, ww = w0 - 1 + tx;
    float v = 0.f;
    if (hh >= 0 && hh < 224 && ww >= 0 && ww < 224)
      v = x[((long)n * 3 + ci) * 50176 + hh * 224 + ww];
    it[ci][ty][tx] = v;
  }
  __syncthreads();
  const int ty = tid >> 4, tx = tid & 15;
  long ob = (((long)n * 224 + h0 + ty) * 224 + (w0 + tx)) * 64;
  for (int cog = 0; cog < 4; ++cog) {
    float acc[16];
    #pragma unroll
    for (int u = 0; u < 16; ++u) acc[u] = bl[cog * 16 + u];
    #pragma unroll
    for (int ci = 0; ci < 3; ++ci)
      #pragma unroll
      for (int kh = 0; kh < 3; ++kh)
        #pragma unroll
        for (int kw = 0; kw < 3; ++kw) {
          float v = it[ci][ty + kh][tx + kw];
          int jj = ci * 9 + kh * 3 + kw;
          #pragma unroll
          for (int u = 0; u < 16; ++u) acc[u] += v * wl[(cog * 16 + u) * 27 + jj];
        }
    short8 s0, s1;
    #pragma unroll
    for (int u = 0; u < 8; ++u) {
      s0[u] = f2s(fmaxf(acc[u], 0.f));
      s1[u] = f2s(fmaxf(acc[8 + u], 0.f));
    }
    *(short8*)(out + ob + cog * 16) = s0;
    *(short8*)(out + ob + cog * 16 + 8) = s1;
  }
}

// ---------------------------------------------------------------- fused weight repack (all 12 MFMA conv layers)
struct RepackMeta {
  const float* src[12];
  long dstOff[12];
  int cinM1[12];
  int cshift[12];
  int cout[12];
};

__global__ __launch_bounds__(256) void repack_all(RepackMeta m, bf16* __restrict__ blob) {
  const int li = blockIdx.y;
  const int co = blockIdx.x;
  if (co >= m.cout[li]) return;
  const int cs = m.cshift[li];
  const int cinM1 = m.cinM1[li];
  const int K = 9 << cs;
  const float* src = m.src[li] + (long)co * (cinM1 + 1) * 9;
  bf16* dst = blob + m.dstOff[li] + (long)co * K;
  for (int k = threadIdx.x; k < K; k += 256) {
    int pos = k >> cs;
    int ci = k & cinM1;
    dst[k] = __float2bfloat16(src[ci * 9 + pos]);
  }
}

// ---------------------------------------------------------------- implicit-GEMM conv (NHWC, bf16 MFMA)
// C[p, co] = sum_k A[p,k] * Wp[co,k];  k = pos*Cin + ci, pos=(kh*3+kw)
// pos-outer / ci-inner k-loop: boundary predicate + address select hoisted
// per position; inner steps are pure pointer bumps (+128 B).
template <int BM, int BN, int WM, int WN, int SPLITK>
__global__ __launch_bounds__(WM* WN * 64) void conv_gemm(
    const bf16* __restrict__ in, const bf16* __restrict__ wp,
    const float* __restrict__ bias, bf16* __restrict__ out,
    float* __restrict__ pout, const bf16* __restrict__ zp,
    int Cin, int cshift, int Cout, int H, int W, int NHW) {
  constexpr int NT = WM * WN * 64;
  constexpr int IA = BM * 8 / NT;   // gload_lds per thread for A tile
  constexpr int IB = BN * 8 / NT;
  __shared__ bf16 lA[BM * 64];
  __shared__ bf16 lB[BN * 64];
  const int tid = threadIdx.x;
  const int lane = tid & 63, wv = tid >> 6;
  const int wr = wv / WN, wc = wv % WN;

  // XCD-aware bijective swizzle (m204) over the x*y grid (independent per z)
  const int gx = gridDim.x;
  const int nwg = gx * gridDim.y;
  const int fid = blockIdx.y * gx + blockIdx.x;
  const int q = nwg >> 3, r = nwg & 7;
  const int xcd = fid & 7, idx = fid >> 3;
  const int swz = (xcd < r ? xcd * (q + 1) : r * (q + 1) + (xcd - r) * q) + idx;
  const int p0 = (swz % gx) * BM;
  const int co0 = (swz / gx) * BN;

  const int K = 9 << cshift;
  const int HW = H * W;
  const int colx = ((tid & 7) ^ ((tid >> 3) & 7)) * 8;

  int baseA[IA]; short hA[IA], wA[IA];
  #pragma unroll
  for (int i = 0; i < IA; ++i) {
    int rr = i * (NT / 8) + (tid >> 3);
    int p = p0 + rr;
    if (p < NHW) {
      int n = p / HW; int rem = p - n * HW; int h = rem / W; int w_ = rem - h * W;
      hA[i] = (short)h; wA[i] = (short)w_;
      baseA[i] = ((n * H + h) * W + w_) * Cin;
    } else { hA[i] = -9999; wA[i] = -9999; baseA[i] = 0; }
  }

  f32x4 acc[4][4];
  #pragma unroll
  for (int m = 0; m < 4; ++m)
    #pragma unroll
    for (int n2 = 0; n2 < 4; ++n2) acc[m][n2] = (f32x4){0.f, 0.f, 0.f, 0.f};

  const int Kper = K / SPLITK;
  const int kBeg = (SPLITK > 1) ? (int)blockIdx.z * Kper : 0;
  const int kEnd = kBeg + Kper;

  // B source pointers: advance 64 elems per k-step (contiguous k)
  const bf16* srcB[IB];
  #pragma unroll
  for (int i = 0; i < IB; ++i) {
    int col = i * (NT / 8) + (tid >> 3);
    srcB[i] = wp + (long)(co0 + col) * K + kBeg + colx;
  }

  int kk = kBeg;
  while (kk < kEnd) {
    const int pos = kk >> cshift;
    const int dh = pos / 3 - 1, dw = pos - (pos / 3) * 3 - 1;
    int posEnd = (pos + 1) << cshift;
    if (posEnd > kEnd) posEnd = kEnd;
    // hoisted per-slot A source pointers for this position
    const bf16* srcA[IA];
    {
      const int doff = (dh * W + dw) * Cin + (kk & (Cin - 1)) + colx;
      #pragma unroll
      for (int i = 0; i < IA; ++i) {
        int hh = hA[i] + dh, ww = wA[i] + dw;
        bool ok = (hh >= 0) & (hh < H) & (ww >= 0) & (ww < W);
        srcA[i] = ok ? (in + baseA[i] + doff) : (zp + colx);
      }
    }
    for (; kk < posEnd; kk += 64) {
      __syncthreads();
      #pragma unroll
      for (int i = 0; i < IA; ++i) {
        gl16(srcA[i], lA + i * (NT * 8) + wv * 512);
        srcA[i] += 64;
      }
      #pragma unroll
      for (int i = 0; i < IB; ++i) {
        gl16(srcB[i], lB + i * (NT * 8) + wv * 512);
        srcB[i] += 64;
      }
      __syncthreads();
      #pragma unroll
      for (int ks = 0; ks < 2; ++ks) {
        const int kb = ks * 64 + (lane >> 4) * 16;  // byte offset in row
        bf16x8 af[4], bfv[4];
        #pragma unroll
        for (int m = 0; m < 4; ++m) {
          int rr = wr * 64 + m * 16 + (lane & 15);
          af[m] = *(const bf16x8*)((const char*)lA + rr * 128 + (kb ^ ((rr & 7) << 4)));
        }
        #pragma unroll
        for (int n2 = 0; n2 < 4; ++n2) {
          int c = wc * 64 + n2 * 16 + (lane & 15);
          bfv[n2] = *(const bf16x8*)((const char*)lB + c * 128 + (kb ^ ((c & 7) << 4)));
        }
        #pragma unroll
        for (int m = 0; m < 4; ++m)
          #pragma unroll
          for (int n2 = 0; n2 < 4; ++n2)
            acc[m][n2] = __builtin_amdgcn_mfma_f32_16x16x32_bf16(af[m], bfv[n2], acc[m][n2], 0, 0, 0);
      }
    }
  }

  // epilogue: C/D layout col=lane&15, row=(lane>>4)*4+q
  if constexpr (SPLITK == 1) {
    #pragma unroll
    for (int m = 0; m < 4; ++m) {
      int pb = p0 + wr * 64 + m * 16 + (lane >> 4) * 4;
      #pragma unroll
      for (int n2 = 0; n2 < 4; ++n2) {
        int co = co0 + wc * 64 + n2 * 16 + (lane & 15);
        float bb = bias[co];
        #pragma unroll
        for (int qq = 0; qq < 4; ++qq) {
          int pp = pb + qq;
          if (pp < NHW)
            out[(long)pp * Cout + co] = __float2bfloat16(fmaxf(acc[m][n2][qq] + bb, 0.f));
        }
      }
    }
  } else {
    float* pb_ = pout + (long)blockIdx.z * NHW * Cout;
    #pragma unroll
    for (int m = 0; m < 4; ++m) {
      int pb = p0 + wr * 64 + m * 16 + (lane >> 4) * 4;
      #pragma unroll
      for (int n2 = 0; n2 < 4; ++n2) {
        int co = co0 + wc * 64 + n2 * 16 + (lane & 15);
        #pragma unroll
        for (int qq = 0; qq < 4; ++qq) {
          int pp = pb + qq;
          if (pp < NHW) pb_[(long)pp * Cout + co] = acc[m][n2][qq];
        }
      }
    }
  }
}

// ---------------------------------------------------------------- split-K reduce: part0+part1+bias, relu, ->bf16
__global__ __launch_bounds__(256) void reduce_split(
    const float* __restrict__ part, const float* __restrict__ bias,
    bf16* __restrict__ out, int NHW, int Cout) {
  long e4 = ((long)blockIdx.x * 256 + threadIdx.x) * 4;
  long total = (long)NHW * Cout;
  if (e4 >= total) return;
  f32x4 a = *(const f32x4*)(part + e4);
  f32x4 b = *(const f32x4*)(part + total + e4);
  f32x4 bv = *(const f32x4*)(bias + (int)(e4 & (Cout - 1)));
  s16x4 r;
  #pragma unroll
  for (int u = 0; u < 4; ++u) r[u] = f2s(fmaxf(a[u] + b[u] + bv[u], 0.f));
  *(s16x4*)(out + e4) = r;
}

// ---------------------------------------------------------------- maxpool 2x2 NHWC (short8 vectors)
__global__ void maxpool_nhwc(const bf16* __restrict__ in, bf16* __restrict__ out,
                             int H, int W, int C, int cshift3, int WC8) {
  const int id = blockIdx.x * 256 + threadIdx.x;
  if (id >= WC8) return;
  const int H2 = H >> 1, W2 = W >> 1;
  const int ho = blockIdx.y, n = blockIdx.z;
  const int wo = id >> cshift3, c8 = id & ((1 << cshift3) - 1);
  const bf16* p = in + (((long)(n * H + 2 * ho) * W) + 2 * wo) * C + c8 * 8;
  short8 a = *(const short8*)p;
  short8 bq = *(const short8*)(p + C);
  short8 c = *(const short8*)(p + (long)W * C);
  short8 d = *(const short8*)(p + (long)W * C + C);
  short8 r;
  #pragma unroll
  for (int u = 0; u < 8; ++u) {
    float m = fmaxf(fmaxf(s2f(a[u]), s2f(bq[u])), fmaxf(s2f(c[u]), s2f(d[u])));
    r[u] = f2s(m);
  }
  *(short8*)(out + ((long)(n * H2 + ho) * W2 + wo) * C + c8 * 8) = r;
}

// ---------------------------------------------------------------- FC1 partial
__global__ __launch_bounds__(256) void fc1_partial(
    const bf16* __restrict__ in, const float* __restrict__ w,
    float* __restrict__ part) {
  const int j0 = blockIdx.x * 1024 + threadIdx.x * 4;
  const int k0 = blockIdx.y * 256;
  __shared__ float ilds[256][16];
  #pragma unroll
  for (int i = 0; i < 16; ++i) {
    int e = i * 256 + threadIdx.x;
    int kk = e >> 4, n = e & 15;
    int k = k0 + kk;
    int cch = k / 49, s = k - cch * 49;
    ilds[kk][n] = s2f(__builtin_bit_cast(short, in[((long)n * 49 + s) * 512 + cch]));
  }
  __syncthreads();
  f32x4 acc[16];
  #pragma unroll
  for (int n = 0; n < 16; ++n) acc[n] = (f32x4){0.f, 0.f, 0.f, 0.f};
  #pragma unroll 4
  for (int kk = 0; kk < 256; ++kk) {
    f32x4 w4 = *(const f32x4*)(w + (long)(k0 + kk) * 4096 + j0);
    #pragma unroll
    for (int n = 0; n < 16; ++n) {
      float v = ilds[kk][n];
      acc[n] += v * w4;
    }
  }
  float* pp = part + (long)blockIdx.y * 16 * 4096;
  #pragma unroll
  for (int n = 0; n < 16; ++n) *(f32x4*)(pp + n * 4096 + j0) = acc[n];
}

// ---------------------------------------------------------------- FC2/FC3 partial (fp32 in, relu-on-read)
__global__ __launch_bounds__(256) void fc23_partial(
    const float* __restrict__ in, const float* __restrict__ w,
    float* __restrict__ part, int fin, int fout) {
  const int j0 = blockIdx.x * 1024 + threadIdx.x * 4;
  const int k0 = blockIdx.y * 64;
  __shared__ float ilds[64][16];
  #pragma unroll
  for (int i = 0; i < 4; ++i) {
    int e = i * 256 + threadIdx.x;
    int kk = e >> 4, n = e & 15;
    ilds[kk][n] = fmaxf(in[(long)n * fin + k0 + kk], 0.f);
  }
  __syncthreads();
  if (j0 >= fout) return;
  f32x4 acc[16];
  #pragma unroll
  for (int n = 0; n < 16; ++n) acc[n] = (f32x4){0.f, 0.f, 0.f, 0.f};
  #pragma unroll 4
  for (int kk = 0; kk < 64; ++kk) {
    f32x4 w4 = *(const f32x4*)(w + (long)(k0 + kk) * fout + j0);
    #pragma unroll
    for (int n = 0; n < 16; ++n) {
      float v = ilds[kk][n];
      acc[n] += v * w4;
    }
  }
  float* pp = part + (long)blockIdx.y * 16 * fout;
  #pragma unroll
  for (int n = 0; n < 16; ++n) *(f32x4*)(pp + n * fout + j0) = acc[n];
}

// ---------------------------------------------------------------- reduce FC partials + bias
__global__ void reduce_fc(const float* __restrict__ part, const float* __restrict__ bias,
                          float* __restrict__ out, int nparts, int fout, int total) {
  int i = blockIdx.x * 256 + threadIdx.x;
  if (i >= total) return;
  int n = i / fout, j = i - n * fout;
  float s = bias[j];
  for (int p = 0; p < nparts; ++p) s += part[((long)p * 16 + n) * fout + j];
  out[i] = s;
}

// ---------------------------------------------------------------- launch
extern "C" void kernel_launch(void* const* d_in, const int* in_sizes, int n_in,
                              void* d_out, int out_size, void* d_ws, size_t ws_size,
                              hipStream_t stream) {
  const float* x = (const float*)d_in[0];
  const float* cw[13]; const float* cb[13];
  for (int i = 0; i < 13; ++i) { cw[i] = (const float*)d_in[1 + 2 * i]; cb[i] = (const float*)d_in[2 + 2 * i]; }
  const float* fw1 = (const float*)d_in[27]; const float* fb1 = (const float*)d_in[28];
  const float* fw2 = (const float*)d_in[29]; const float* fb2 = (const float*)d_in[30];
  const float* fw3 = (const float*)d_in[31]; const float* fb3 = (const float*)d_in[32];
  float* outp = (float*)d_out;

  const size_t REGION = 102760448;  // 51,380,224 bf16 elems
  char* wsb = (char*)d_ws;
  bf16* A = (bf16*)wsb;
  bf16* B = (bf16*)(wsb + REGION);
  char* ST = wsb + 2 * REGION;
  bf16* zp = (bf16*)ST;                          // 4 KB zero page
  bf16* WBLOB = (bf16*)(ST + 4096);              // ~29.4 MB repacked weights
  char* ST2 = ST + 4096 + 31 * 1024 * 1024;
  float* F1 = (float*)ST2;                       // 16x4096 fp32
  float* F2 = F1 + 16 * 4096;
  float* PS = F2 + 16 * 4096;                    // split-K partials: 2*3136*512 fp32 = 12.85 MB

  struct LayerCfg { int cin, cs, cout, H, W; };
  const LayerCfg L[12] = {
      {64, 6, 64, 224, 224},  {64, 6, 128, 112, 112}, {128, 7, 128, 112, 112},
      {128, 7, 256, 56, 56},  {256, 8, 256, 56, 56},  {256, 8, 256, 56, 56},
      {256, 8, 512, 28, 28},  {512, 9, 512, 28, 28},  {512, 9, 512, 28, 28},
      {512, 9, 512, 14, 14},  {512, 9, 512, 14, 14},  {512, 9, 512, 14, 14}};
  const bool poolAfter[12] = {true, false, true, false, false, true, false, false, true, false, false, true};

  // ---- fused weight repack
  RepackMeta rm;
  long off = 0;
  long offs[12];
  for (int li = 0; li < 12; ++li) {
    rm.src[li] = cw[li + 1];
    rm.cinM1[li] = L[li].cin - 1;
    rm.cshift[li] = L[li].cs;
    rm.cout[li] = L[li].cout;
    rm.dstOff[li] = off;
    offs[li] = off;
    off += (long)L[li].cout * (9 << L[li].cs);
  }
  zerofill<<<4, 256, 0, stream>>>((float*)zp, 1024);
  repack_all<<<dim3(512, 12), 256, 0, stream>>>(rm, WBLOB);

  conv1_first<<<dim3(14, 14, 16), 256, 0, stream>>>(x, cw[0], cb[0], A);

  bf16* cur = A;
  bf16* oth = B;
  for (int li = 0; li < 12; ++li) {
    const LayerCfg& c = L[li];
    bf16* wb = WBLOB + offs[li];
    const int NHW = 16 * c.H * c.W;
    if (li == 0) {
      // 224x224, N=64: 3136 WGs, 4-wave
      conv_gemm<256, 64, 4, 1, 1><<<dim3(NHW / 256, 1), 256, 0, stream>>>(
          cur, wb, cb[li + 1], oth, nullptr, zp, c.cin, c.cs, c.cout, c.H, c.W, NHW);
    } else if (li <= 2) {
      // 112x112, N=128: 784 WGs, 8-wave big-M tile
      conv_gemm<256, 128, 4, 2, 1><<<dim3(NHW / 256, 1), 512, 0, stream>>>(
          cur, wb, cb[li + 1], oth, nullptr, zp, c.cin, c.cs, c.cout, c.H, c.W, NHW);
    } else if (li <= 5) {
      // 56x56, N=256: 392 WGs, 8-wave wide-N tile
      conv_gemm<128, 256, 2, 4, 1><<<dim3(NHW / 128, 1), 512, 0, stream>>>(
          cur, wb, cb[li + 1], oth, nullptr, zp, c.cin, c.cs, c.cout, c.H, c.W, NHW);
    } else if (li <= 8) {
      // 28x28, N=512: 392 WGs, 4-wave
      conv_gemm<128, 128, 2, 2, 1><<<dim3((NHW + 127) / 128, c.cout / 128), 256, 0, stream>>>(
          cur, wb, cb[li + 1], oth, nullptr, zp, c.cin, c.cs, c.cout, c.H, c.W, NHW);
    } else {
      // 14x14, N=512: split-K=2 -> 200 WGs + deterministic reduce
      conv_gemm<128, 128, 2, 2, 2><<<dim3((NHW + 127) / 128, c.cout / 128, 2), 256, 0, stream>>>(
          cur, wb, cb[li + 1], nullptr, PS, zp, c.cin, c.cs, c.cout, c.H, c.W, NHW);
      long tot = (long)NHW * c.cout;
      reduce_split<<<(int)((tot / 4 + 255) / 256), 256, 0, stream>>>(PS, cb[li + 1], oth, NHW, c.cout);
    }
    bf16* t = cur; cur = oth; oth = t;
    if (poolAfter[li]) {
      int cs3 = (c.cout == 64) ? 3 : (c.cout == 128) ? 4 : (c.cout == 256) ? 5 : 6;
      int W2 = c.W / 2, H2 = c.H / 2;
      int WC8 = W2 << cs3;
      maxpool_nhwc<<<dim3((WC8 + 255) / 256, H2, 16), 256, 0, stream>>>(cur, oth, c.H, c.W, c.cout, cs3, WC8);
      t = cur; cur = oth; oth = t;
    }
  }
  // cur = pool5 output [16,7,7,512] NHWC bf16, lives in region B.
  // Region A is free during the FC phase -> partial buffers overlay it.
  float* P1 = (float*)A;                                  // 98*16*4096*4 = 25.7 MB
  float* P2 = (float*)((char*)A + 32u * 1024 * 1024);     // 64*16*4096*4 = 16.8 MB
  float* P3 = (float*)((char*)A + 52u * 1024 * 1024);     // 64*16*1000*4 =  4.1 MB

  fc1_partial<<<dim3(4, 98), 256, 0, stream>>>(cur, fw1, P1);
  reduce_fc<<<(16 * 4096 + 255) / 256, 256, 0, stream>>>(P1, fb1, F1, 98, 4096, 16 * 4096);
  fc23_partial<<<dim3(4, 64), 256, 0, stream>>>(F1, fw2, P2, 4096, 4096);
  reduce_fc<<<(16 * 4096 + 255) / 256, 256, 0, stream>>>(P2, fb2, F2, 64, 4096, 16 * 4096);
  fc23_partial<<<dim3(1, 64), 256, 0, stream>>>(F2, fw3, P3, 4096, 1000);
  reduce_fc<<<(16 * 1000 + 255) / 256, 256, 0, stream>>>(P3, fb3, outp, 64, 1000, 16 * 1000);
}

// Round 7
// 1251.613 us; speedup vs baseline: 155.0622x; 1.0211x over previous
//
#include <hip/hip_runtime.h>
#include <hip/hip_bf16.h>

typedef __hip_bfloat16 bf16;
typedef __attribute__((ext_vector_type(4))) short s16x4;
typedef __attribute__((ext_vector_type(8))) short short8;
typedef __attribute__((ext_vector_type(8))) __bf16 bf16x8;
typedef __attribute__((ext_vector_type(4))) float f32x4;

__device__ __forceinline__ float s2f(short s) {
  return __builtin_bit_cast(float, (unsigned)((unsigned short)s) << 16);
}
__device__ __forceinline__ short f2s(float f) {
  return __builtin_bit_cast(short, __float2bfloat16(f));
}

__device__ __forceinline__ void gl16(const bf16* g, bf16* l) {
  __builtin_amdgcn_global_load_lds(
      (const __attribute__((address_space(1))) void*)g,
      (__attribute__((address_space(3))) void*)l, 16, 0, 0);
}

// ---------------------------------------------------------------- zero fill (zpage)
__global__ void zerofill(float* p, int n) {
  int i = blockIdx.x * 256 + threadIdx.x;
  if (i < n) p[i] = 0.f;
}

// ---------------------------------------------------------------- layer 1: 3->64, fp32 NCHW in, bf16 NHWC out
__global__ __launch_bounds__(256) void conv1_first(
    const float* __restrict__ x, const float* __restrict__ w,
    const float* __restrict__ b, bf16* __restrict__ out) {
  __shared__ float it[3][18][18];
  __shared__ float wl[1728];
  __shared__ float bl[64];
  const int tid = threadIdx.x;
  const int n = blockIdx.z;
  const int h0 = blockIdx.y * 16, w0 = blockIdx.x * 16;
  for (int i = tid; i < 1728; i += 256) wl[i] = w[i];
  if (tid < 64) bl[tid] = b[tid];
  for (int i = tid; i < 972; i += 256) {
    int ci = i / 324; int r = i - ci * 324; int ty = r / 18, tx = r - ty * 18;
    int hh = h0 - 1 + ty, ww = w0 - 1 + tx;
    float v = 0.f;
    if (hh >= 0 && hh < 224 && ww >= 0 && ww < 224)
      v = x[((long)n * 3 + ci) * 50176 + hh * 224 + ww];
    it[ci][ty][tx] = v;
  }
  __syncthreads();
  const int ty = tid >> 4, tx = tid & 15;
  long ob = (((long)n * 224 + h0 + ty) * 224 + (w0 + tx)) * 64;
  for (int cog = 0; cog < 4; ++cog) {
    float acc[16];
    #pragma unroll
    for (int u = 0; u < 16; ++u) acc[u] = bl[cog * 16 + u];
    #pragma unroll
    for (int ci = 0; ci < 3; ++ci)
      #pragma unroll
      for (int kh = 0; kh < 3; ++kh)
        #pragma unroll
        for (int kw = 0; kw < 3; ++kw) {
          float v = it[ci][ty + kh][tx + kw];
          int jj = ci * 9 + kh * 3 + kw;
          #pragma unroll
          for (int u = 0; u < 16; ++u) acc[u] += v * wl[(cog * 16 + u) * 27 + jj];
        }
    short8 s0, s1;
    #pragma unroll
    for (int u = 0; u < 8; ++u) {
      s0[u] = f2s(fmaxf(acc[u], 0.f));
      s1[u] = f2s(fmaxf(acc[8 + u], 0.f));
    }
    *(short8*)(out + ob + cog * 16) = s0;
    *(short8*)(out + ob + cog * 16 + 8) = s1;
  }
}

// ---------------------------------------------------------------- fused weight repack (all 12 MFMA conv layers)
struct RepackMeta {
  const float* src[12];
  long dstOff[12];
  int cinM1[12];
  int cshift[12];
  int cout[12];
};

__global__ __launch_bounds__(256) void repack_all(RepackMeta m, bf16* __restrict__ blob) {
  const int li = blockIdx.y;
  const int co = blockIdx.x;
  if (co >= m.cout[li]) return;
  const int cs = m.cshift[li];
  const int cinM1 = m.cinM1[li];
  const int K = 9 << cs;
  const float* src = m.src[li] + (long)co * (cinM1 + 1) * 9;
  bf16* dst = blob + m.dstOff[li] + (long)co * K;
  for (int k = threadIdx.x; k < K; k += 256) {
    int pos = k >> cs;
    int ci = k & cinM1;
    dst[k] = __float2bfloat16(src[ci * 9 + pos]);
  }
}

// ---------------------------------------------------------------- implicit-GEMM conv (NHWC, bf16 MFMA)
// C[p, co] = sum_k A[p,k] * Wp[co,k];  k = pos*Cin + ci, pos=(kh*3+kw)
// pos-outer / ci-inner k-loop: boundary predicate + address select hoisted.
template <int BM, int BN, int WM, int WN, int SPLITK>
__global__ __launch_bounds__(WM* WN * 64) void conv_gemm(
    const bf16* __restrict__ in, const bf16* __restrict__ wp,
    const float* __restrict__ bias, bf16* __restrict__ out,
    float* __restrict__ pout, const bf16* __restrict__ zp,
    int Cin, int cshift, int Cout, int H, int W, int NHW) {
  constexpr int NT = WM * WN * 64;
  constexpr int IA = BM * 8 / NT;   // gload_lds per thread for A tile
  constexpr int IB = BN * 8 / NT;
  __shared__ bf16 lA[BM * 64];
  __shared__ bf16 lB[BN * 64];
  const int tid = threadIdx.x;
  const int lane = tid & 63, wv = tid >> 6;
  const int wr = wv / WN, wc = wv % WN;

  // XCD-aware bijective swizzle (m204) over the x*y grid (independent per z)
  const int gx = gridDim.x;
  const int nwg = gx * gridDim.y;
  const int fid = blockIdx.y * gx + blockIdx.x;
  const int q = nwg >> 3, r = nwg & 7;
  const int xcd = fid & 7, idx = fid >> 3;
  const int swz = (xcd < r ? xcd * (q + 1) : r * (q + 1) + (xcd - r) * q) + idx;
  const int p0 = (swz % gx) * BM;
  const int co0 = (swz / gx) * BN;

  const int K = 9 << cshift;
  const int HW = H * W;
  const int colx = ((tid & 7) ^ ((tid >> 3) & 7)) * 8;

  int baseA[IA]; short hA[IA], wA[IA];
  #pragma unroll
  for (int i = 0; i < IA; ++i) {
    int rr = i * (NT / 8) + (tid >> 3);
    int p = p0 + rr;
    if (p < NHW) {
      int n = p / HW; int rem = p - n * HW; int h = rem / W; int w_ = rem - h * W;
      hA[i] = (short)h; wA[i] = (short)w_;
      baseA[i] = ((n * H + h) * W + w_) * Cin;
    } else { hA[i] = -9999; wA[i] = -9999; baseA[i] = 0; }
  }

  f32x4 acc[4][4];
  #pragma unroll
  for (int m = 0; m < 4; ++m)
    #pragma unroll
    for (int n2 = 0; n2 < 4; ++n2) acc[m][n2] = (f32x4){0.f, 0.f, 0.f, 0.f};

  const int Kper = K / SPLITK;
  const int kBeg = (SPLITK > 1) ? (int)blockIdx.z * Kper : 0;
  const int kEnd = kBeg + Kper;

  // B source pointers: advance 64 elems per k-step (contiguous k)
  const bf16* srcB[IB];
  #pragma unroll
  for (int i = 0; i < IB; ++i) {
    int col = i * (NT / 8) + (tid >> 3);
    srcB[i] = wp + (long)(co0 + col) * K + kBeg + colx;
  }

  int kk = kBeg;
  while (kk < kEnd) {
    const int pos = kk >> cshift;
    const int dh = pos / 3 - 1, dw = pos - (pos / 3) * 3 - 1;
    int posEnd = (pos + 1) << cshift;
    if (posEnd > kEnd) posEnd = kEnd;
    // hoisted per-slot A source pointers for this position
    const bf16* srcA[IA];
    {
      const int doff = (dh * W + dw) * Cin + (kk & (Cin - 1)) + colx;
      #pragma unroll
      for (int i = 0; i < IA; ++i) {
        int hh = hA[i] + dh, ww = wA[i] + dw;
        bool ok = (hh >= 0) & (hh < H) & (ww >= 0) & (ww < W);
        srcA[i] = ok ? (in + baseA[i] + doff) : (zp + colx);
      }
    }
    for (; kk < posEnd; kk += 64) {
      __syncthreads();
      #pragma unroll
      for (int i = 0; i < IA; ++i) {
        gl16(srcA[i], lA + i * (NT * 8) + wv * 512);
        srcA[i] += 64;
      }
      #pragma unroll
      for (int i = 0; i < IB; ++i) {
        gl16(srcB[i], lB + i * (NT * 8) + wv * 512);
        srcB[i] += 64;
      }
      __syncthreads();
      #pragma unroll
      for (int ks = 0; ks < 2; ++ks) {
        const int kb = ks * 64 + (lane >> 4) * 16;  // byte offset in row
        bf16x8 af[4], bfv[4];
        #pragma unroll
        for (int m = 0; m < 4; ++m) {
          int rr = wr * 64 + m * 16 + (lane & 15);
          af[m] = *(const bf16x8*)((const char*)lA + rr * 128 + (kb ^ ((rr & 7) << 4)));
        }
        #pragma unroll
        for (int n2 = 0; n2 < 4; ++n2) {
          int c = wc * 64 + n2 * 16 + (lane & 15);
          bfv[n2] = *(const bf16x8*)((const char*)lB + c * 128 + (kb ^ ((c & 7) << 4)));
        }
        #pragma unroll
        for (int m = 0; m < 4; ++m)
          #pragma unroll
          for (int n2 = 0; n2 < 4; ++n2)
            acc[m][n2] = __builtin_amdgcn_mfma_f32_16x16x32_bf16(af[m], bfv[n2], acc[m][n2], 0, 0, 0);
      }
    }
  }

  // epilogue: C/D layout col=lane&15, row=(lane>>4)*4+q
  if constexpr (SPLITK == 1) {
    #pragma unroll
    for (int m = 0; m < 4; ++m) {
      int pb = p0 + wr * 64 + m * 16 + (lane >> 4) * 4;
      #pragma unroll
      for (int n2 = 0; n2 < 4; ++n2) {
        int co = co0 + wc * 64 + n2 * 16 + (lane & 15);
        float bb = bias[co];
        #pragma unroll
        for (int qq = 0; qq < 4; ++qq) {
          int pp = pb + qq;
          if (pp < NHW)
            out[(long)pp * Cout + co] = __float2bfloat16(fmaxf(acc[m][n2][qq] + bb, 0.f));
        }
      }
    }
  } else {
    float* pb_ = pout + (long)blockIdx.z * NHW * Cout;
    #pragma unroll
    for (int m = 0; m < 4; ++m) {
      int pb = p0 + wr * 64 + m * 16 + (lane >> 4) * 4;
      #pragma unroll
      for (int n2 = 0; n2 < 4; ++n2) {
        int co = co0 + wc * 64 + n2 * 16 + (lane & 15);
        #pragma unroll
        for (int qq = 0; qq < 4; ++qq) {
          int pp = pb + qq;
          if (pp < NHW) pb_[(long)pp * Cout + co] = acc[m][n2][qq];
        }
      }
    }
  }
}

// ---------------------------------------------------------------- split-K reduce (+bias+relu+bf16), optionally fused 2x2 maxpool
template <int NPARTS, bool POOL>
__global__ __launch_bounds__(256) void reduce_split(
    const float* __restrict__ part, const float* __restrict__ bias,
    bf16* __restrict__ out, int NHW, int H, int W, int C) {
  const long total = (long)NHW * C;  // per-part stride
  if constexpr (!POOL) {
    long e4 = ((long)blockIdx.x * 256 + threadIdx.x) * 4;
    if (e4 >= total) return;
    f32x4 s = *(const f32x4*)(part + e4);
    #pragma unroll
    for (int p2 = 1; p2 < NPARTS; ++p2) {
      f32x4 b = *(const f32x4*)(part + (long)p2 * total + e4);
      s += b;
    }
    f32x4 bv = *(const f32x4*)(bias + (int)(e4 & (C - 1)));
    s16x4 r;
    #pragma unroll
    for (int u = 0; u < 4; ++u) r[u] = f2s(fmaxf(s[u] + bv[u], 0.f));
    *(s16x4*)(out + e4) = r;
  } else {
    const int H2 = H >> 1, W2 = W >> 1;
    long id4 = ((long)blockIdx.x * 256 + threadIdx.x) * 4;
    long ptotal = ((long)NHW / 4) * C;
    if (id4 >= ptotal) return;
    int c4 = (int)(id4 & (C - 1));
    long rest = id4 / C;
    int wo = (int)(rest % W2);
    long t2 = rest / W2;
    int ho = (int)(t2 % H2);
    int n = (int)(t2 / H2);
    f32x4 bv = *(const f32x4*)(bias + c4);
    f32x4 mx;
    #pragma unroll
    for (int dy = 0; dy < 2; ++dy)
      #pragma unroll
      for (int dx = 0; dx < 2; ++dx) {
        long p = ((long)n * H + 2 * ho + dy) * W + 2 * wo + dx;
        long e = p * C + c4;
        f32x4 s = *(const f32x4*)(part + e);
        #pragma unroll
        for (int p2 = 1; p2 < NPARTS; ++p2) {
          f32x4 b = *(const f32x4*)(part + (long)p2 * total + e);
          s += b;
        }
        s += bv;
        if (dy == 0 && dx == 0) mx = s;
        else {
          #pragma unroll
          for (int u = 0; u < 4; ++u) mx[u] = fmaxf(mx[u], s[u]);
        }
      }
    s16x4 r;
    #pragma unroll
    for (int u = 0; u < 4; ++u) r[u] = f2s(fmaxf(mx[u], 0.f));
    *(s16x4*)(out + ((long)(n * H2 + ho) * W2 + wo) * C + c4) = r;
  }
}

// ---------------------------------------------------------------- maxpool 2x2 NHWC (short8 vectors)
__global__ void maxpool_nhwc(const bf16* __restrict__ in, bf16* __restrict__ out,
                             int H, int W, int C, int cshift3, int WC8) {
  const int id = blockIdx.x * 256 + threadIdx.x;
  if (id >= WC8) return;
  const int H2 = H >> 1, W2 = W >> 1;
  const int ho = blockIdx.y, n = blockIdx.z;
  const int wo = id >> cshift3, c8 = id & ((1 << cshift3) - 1);
  const bf16* p = in + (((long)(n * H + 2 * ho) * W) + 2 * wo) * C + c8 * 8;
  short8 a = *(const short8*)p;
  short8 bq = *(const short8*)(p + C);
  short8 c = *(const short8*)(p + (long)W * C);
  short8 d = *(const short8*)(p + (long)W * C + C);
  short8 r;
  #pragma unroll
  for (int u = 0; u < 8; ++u) {
    float m = fmaxf(fmaxf(s2f(a[u]), s2f(bq[u])), fmaxf(s2f(c[u]), s2f(d[u])));
    r[u] = f2s(m);
  }
  *(short8*)(out + ((long)(n * H2 + ho) * W2 + wo) * C + c8 * 8) = r;
}

// ---------------------------------------------------------------- FC1 partial
__global__ __launch_bounds__(256) void fc1_partial(
    const bf16* __restrict__ in, const float* __restrict__ w,
    float* __restrict__ part) {
  const int j0 = blockIdx.x * 1024 + threadIdx.x * 4;
  const int k0 = blockIdx.y * 256;
  __shared__ float ilds[256][16];
  #pragma unroll
  for (int i = 0; i < 16; ++i) {
    int e = i * 256 + threadIdx.x;
    int kk = e >> 4, n = e & 15;
    int k = k0 + kk;
    int cch = k / 49, s = k - cch * 49;
    ilds[kk][n] = s2f(__builtin_bit_cast(short, in[((long)n * 49 + s) * 512 + cch]));
  }
  __syncthreads();
  f32x4 acc[16];
  #pragma unroll
  for (int n = 0; n < 16; ++n) acc[n] = (f32x4){0.f, 0.f, 0.f, 0.f};
  #pragma unroll 4
  for (int kk = 0; kk < 256; ++kk) {
    f32x4 w4 = *(const f32x4*)(w + (long)(k0 + kk) * 4096 + j0);
    #pragma unroll
    for (int n = 0; n < 16; ++n) {
      float v = ilds[kk][n];
      acc[n] += v * w4;
    }
  }
  float* pp = part + (long)blockIdx.y * 16 * 4096;
  #pragma unroll
  for (int n = 0; n < 16; ++n) *(f32x4*)(pp + n * 4096 + j0) = acc[n];
}

// ---------------------------------------------------------------- FC2/FC3 partial (fp32 in, relu-on-read)
__global__ __launch_bounds__(256) void fc23_partial(
    const float* __restrict__ in, const float* __restrict__ w,
    float* __restrict__ part, int fin, int fout) {
  const int j0 = blockIdx.x * 1024 + threadIdx.x * 4;
  const int k0 = blockIdx.y * 64;
  __shared__ float ilds[64][16];
  #pragma unroll
  for (int i = 0; i < 4; ++i) {
    int e = i * 256 + threadIdx.x;
    int kk = e >> 4, n = e & 15;
    ilds[kk][n] = fmaxf(in[(long)n * fin + k0 + kk], 0.f);
  }
  __syncthreads();
  if (j0 >= fout) return;
  f32x4 acc[16];
  #pragma unroll
  for (int n = 0; n < 16; ++n) acc[n] = (f32x4){0.f, 0.f, 0.f, 0.f};
  #pragma unroll 4
  for (int kk = 0; kk < 64; ++kk) {
    f32x4 w4 = *(const f32x4*)(w + (long)(k0 + kk) * fout + j0);
    #pragma unroll
    for (int n = 0; n < 16; ++n) {
      float v = ilds[kk][n];
      acc[n] += v * w4;
    }
  }
  float* pp = part + (long)blockIdx.y * 16 * fout;
  #pragma unroll
  for (int n = 0; n < 16; ++n) *(f32x4*)(pp + n * fout + j0) = acc[n];
}

// ---------------------------------------------------------------- reduce FC partials + bias
__global__ void reduce_fc(const float* __restrict__ part, const float* __restrict__ bias,
                          float* __restrict__ out, int nparts, int fout, int total) {
  int i = blockIdx.x * 256 + threadIdx.x;
  if (i >= total) return;
  int n = i / fout, j = i - n * fout;
  float s = bias[j];
  for (int p = 0; p < nparts; ++p) s += part[((long)p * 16 + n) * fout + j];
  out[i] = s;
}

// ---------------------------------------------------------------- launch
extern "C" void kernel_launch(void* const* d_in, const int* in_sizes, int n_in,
                              void* d_out, int out_size, void* d_ws, size_t ws_size,
                              hipStream_t stream) {
  const float* x = (const float*)d_in[0];
  const float* cw[13]; const float* cb[13];
  for (int i = 0; i < 13; ++i) { cw[i] = (const float*)d_in[1 + 2 * i]; cb[i] = (const float*)d_in[2 + 2 * i]; }
  const float* fw1 = (const float*)d_in[27]; const float* fb1 = (const float*)d_in[28];
  const float* fw2 = (const float*)d_in[29]; const float* fb2 = (const float*)d_in[30];
  const float* fw3 = (const float*)d_in[31]; const float* fb3 = (const float*)d_in[32];
  float* outp = (float*)d_out;

  const size_t REGION = 102760448;  // 51,380,224 bf16 elems
  char* wsb = (char*)d_ws;
  bf16* A = (bf16*)wsb;
  bf16* B = (bf16*)(wsb + REGION);
  char* ST = wsb + 2 * REGION;
  bf16* zp = (bf16*)ST;                          // 4 KB zero page
  bf16* WBLOB = (bf16*)(ST + 4096);              // ~29.4 MB repacked weights
  char* ST2 = ST + 4096 + 31 * 1024 * 1024;
  float* F1 = (float*)ST2;                       // 16x4096 fp32
  float* F2 = F1 + 16 * 4096;
  float* PS = F2 + 16 * 4096;                    // split-K partials (<= 2*12544*512 fp32 = 51.4 MB)

  struct LayerCfg { int cin, cs, cout, H, W; };
  const LayerCfg L[12] = {
      {64, 6, 64, 224, 224},  {64, 6, 128, 112, 112}, {128, 7, 128, 112, 112},
      {128, 7, 256, 56, 56},  {256, 8, 256, 56, 56},  {256, 8, 256, 56, 56},
      {256, 8, 512, 28, 28},  {512, 9, 512, 28, 28},  {512, 9, 512, 28, 28},
      {512, 9, 512, 14, 14},  {512, 9, 512, 14, 14},  {512, 9, 512, 14, 14}};
  const bool poolAfter[12] = {true, false, true, false, false, true, false, false, true, false, false, true};

  // ---- fused weight repack
  RepackMeta rm;
  long off = 0;
  long offs[12];
  for (int li = 0; li < 12; ++li) {
    rm.src[li] = cw[li + 1];
    rm.cinM1[li] = L[li].cin - 1;
    rm.cshift[li] = L[li].cs;
    rm.cout[li] = L[li].cout;
    rm.dstOff[li] = off;
    offs[li] = off;
    off += (long)L[li].cout * (9 << L[li].cs);
  }
  zerofill<<<4, 256, 0, stream>>>((float*)zp, 1024);
  repack_all<<<dim3(512, 12), 256, 0, stream>>>(rm, WBLOB);

  conv1_first<<<dim3(14, 14, 16), 256, 0, stream>>>(x, cw[0], cb[0], A);

  bf16* cur = A;
  bf16* oth = B;
  for (int li = 0; li < 12; ++li) {
    const LayerCfg& c = L[li];
    bf16* wb = WBLOB + offs[li];
    const int NHW = 16 * c.H * c.W;
    const bool fusedPool = poolAfter[li] && li >= 6;  // L8 (pool4), L11 (pool5)
    if (li == 0) {
      // 224x224, N=64: 3136 WGs, 4-wave
      conv_gemm<256, 64, 4, 1, 1><<<dim3(NHW / 256, 1), 256, 0, stream>>>(
          cur, wb, cb[li + 1], oth, nullptr, zp, c.cin, c.cs, c.cout, c.H, c.W, NHW);
    } else if (li <= 2) {
      // 112x112, N=128: 1568 WGs, 4-wave (tail-quantization fix vs 784x8-wave)
      conv_gemm<128, 128, 2, 2, 1><<<dim3(NHW / 128, c.cout / 128), 256, 0, stream>>>(
          cur, wb, cb[li + 1], oth, nullptr, zp, c.cin, c.cs, c.cout, c.H, c.W, NHW);
    } else if (li <= 5) {
      // 56x56, N=256: 392 WGs, 8-wave wide-N tile
      conv_gemm<128, 256, 2, 4, 1><<<dim3(NHW / 128, 1), 512, 0, stream>>>(
          cur, wb, cb[li + 1], oth, nullptr, zp, c.cin, c.cs, c.cout, c.H, c.W, NHW);
    } else if (li <= 8) {
      // 28x28, N=512: split-K=2 -> 784 WGs (all-resident) + reduce (fused pool on L8)
      conv_gemm<128, 128, 2, 2, 2><<<dim3((NHW + 127) / 128, c.cout / 128, 2), 256, 0, stream>>>(
          cur, wb, cb[li + 1], nullptr, PS, zp, c.cin, c.cs, c.cout, c.H, c.W, NHW);
      if (fusedPool) {
        long pt = ((long)NHW / 4) * c.cout;
        reduce_split<2, true><<<(int)((pt / 4 + 255) / 256), 256, 0, stream>>>(
            PS, cb[li + 1], oth, NHW, c.H, c.W, c.cout);
      } else {
        long tot = (long)NHW * c.cout;
        reduce_split<2, false><<<(int)((tot / 4 + 255) / 256), 256, 0, stream>>>(
            PS, cb[li + 1], oth, NHW, c.H, c.W, c.cout);
      }
    } else {
      // 14x14, N=512: split-K=4 -> 400 WGs + reduce (fused pool on L11)
      conv_gemm<128, 128, 2, 2, 4><<<dim3((NHW + 127) / 128, c.cout / 128, 4), 256, 0, stream>>>(
          cur, wb, cb[li + 1], nullptr, PS, zp, c.cin, c.cs, c.cout, c.H, c.W, NHW);
      if (fusedPool) {
        long pt = ((long)NHW / 4) * c.cout;
        reduce_split<4, true><<<(int)((pt / 4 + 255) / 256), 256, 0, stream>>>(
            PS, cb[li + 1], oth, NHW, c.H, c.W, c.cout);
      } else {
        long tot = (long)NHW * c.cout;
        reduce_split<4, false><<<(int)((tot / 4 + 255) / 256), 256, 0, stream>>>(
            PS, cb[li + 1], oth, NHW, c.H, c.W, c.cout);
      }
    }
    bf16* t = cur; cur = oth; oth = t;
    if (poolAfter[li] && !fusedPool) {
      int cs3 = (c.cout == 64) ? 3 : (c.cout == 128) ? 4 : (c.cout == 256) ? 5 : 6;
      int W2 = c.W / 2, H2 = c.H / 2;
      int WC8 = W2 << cs3;
      maxpool_nhwc<<<dim3((WC8 + 255) / 256, H2, 16), 256, 0, stream>>>(cur, oth, c.H, c.W, c.cout, cs3, WC8);
      t = cur; cur = oth; oth = t;
    }
  }
  // cur = pool5 output [16,7,7,512] NHWC bf16.
  // The other ping-pong region is free during the FC phase -> partial buffers overlay it.
  float* P1 = (float*)oth;
  float* P2 = (float*)((char*)oth + 32u * 1024 * 1024);
  float* P3 = (float*)((char*)oth + 52u * 1024 * 1024);

  fc1_partial<<<dim3(4, 98), 256, 0, stream>>>(cur, fw1, P1);
  reduce_fc<<<(16 * 4096 + 255) / 256, 256, 0, stream>>>(P1, fb1, F1, 98, 4096, 16 * 4096);
  fc23_partial<<<dim3(4, 64), 256, 0, stream>>>(F1, fw2, P2, 4096, 4096);
  reduce_fc<<<(16 * 4096 + 255) / 256, 256, 0, stream>>>(P2, fb2, F2, 64, 4096, 16 * 4096);
  fc23_partial<<<dim3(1, 64), 256, 0, stream>>>(F2, fw3, P3, 4096, 1000);
  reduce_fc<<<(16 * 1000 + 255) / 256, 256, 0, stream>>>(P3, fb3, outp, 64, 1000, 16 * 1000);
}